// Round 2
// baseline (548.794 us; speedup 1.0000x reference)
//
#include <hip/hip_runtime.h>

typedef unsigned int u32;

#define BB  4
#define LL  32777
#define CCH 256
#define MM  4097
#define MM2 512

// ---------- prep: transpose conv weights [o][ci][t] -> [o][t][ci] ----------
__global__ __launch_bounds__(256) void prep_wt(const float* __restrict__ w1,
                                               const float* __restrict__ w2,
                                               float* __restrict__ wt1,
                                               float* __restrict__ wt2) {
    int idx = blockIdx.x * 256 + threadIdx.x;      // 0..131071
    int which = idx >> 16;
    int i = idx & 65535;
    int o = i >> 8, r = i & 255, t = r >> 6, ci = r & 63;
    const float* src = which ? w2 : w1;
    float* dst = which ? wt2 : wt1;
    dst[i] = src[o * 256 + ci * 4 + t];            // dst[o*256 + t*64 + ci]
}

// ---------- GEMM: C(2048x256) = relu(A(2048x256) @ W(256x256) + b) ----------
__global__ __launch_bounds__(256) void gemm_relu_k(const float* __restrict__ A,
                                                   const float* __restrict__ W,
                                                   const float* __restrict__ bias,
                                                   float* __restrict__ C) {
    __shared__ float sh_at[256][16];   // [k][row]
    int tid = threadIdx.x;
    int row0 = blockIdx.x * 16;
    {
        int r = tid >> 4, j = tid & 15;
        const float4* a4 = (const float4*)(A + (size_t)(row0 + r) * 256 + j * 16);
        #pragma unroll
        for (int kk = 0; kk < 4; ++kk) {
            float4 v = a4[kk];
            sh_at[j * 16 + kk * 4 + 0][r] = v.x;
            sh_at[j * 16 + kk * 4 + 1][r] = v.y;
            sh_at[j * 16 + kk * 4 + 2][r] = v.z;
            sh_at[j * 16 + kk * 4 + 3][r] = v.w;
        }
    }
    __syncthreads();
    int o = tid;
    float bo = bias[o];
    float acc[16];
    #pragma unroll
    for (int i = 0; i < 16; ++i) acc[i] = bo;
    #pragma unroll 4
    for (int k = 0; k < 256; ++k) {
        float w = W[k * 256 + o];
        const float4* ap = (const float4*)&sh_at[k][0];   // wave-uniform broadcast
        float4 a0 = ap[0], a1 = ap[1], a2 = ap[2], a3 = ap[3];
        acc[0]  = fmaf(a0.x, w, acc[0]);  acc[1]  = fmaf(a0.y, w, acc[1]);
        acc[2]  = fmaf(a0.z, w, acc[2]);  acc[3]  = fmaf(a0.w, w, acc[3]);
        acc[4]  = fmaf(a1.x, w, acc[4]);  acc[5]  = fmaf(a1.y, w, acc[5]);
        acc[6]  = fmaf(a1.z, w, acc[6]);  acc[7]  = fmaf(a1.w, w, acc[7]);
        acc[8]  = fmaf(a2.x, w, acc[8]);  acc[9]  = fmaf(a2.y, w, acc[9]);
        acc[10] = fmaf(a2.z, w, acc[10]); acc[11] = fmaf(a2.w, w, acc[11]);
        acc[12] = fmaf(a3.x, w, acc[12]); acc[13] = fmaf(a3.y, w, acc[13]);
        acc[14] = fmaf(a3.z, w, acc[14]); acc[15] = fmaf(a3.w, w, acc[15]);
    }
    float* cp = C + (size_t)row0 * 256 + o;
    #pragma unroll
    for (int i = 0; i < 16; ++i) cp[i * 256] = fmaxf(acc[i], 0.f);
}

// ---------- Layer 1: attention + agg + grouped conv, Q=4 positions/block ----------
__global__ __launch_bounds__(256) void layer1_k(
    const float* __restrict__ x, const float* __restrict__ watt, const float* __restrict__ batt,
    const float* __restrict__ wt1, const float* __restrict__ bagg1,
    const float* __restrict__ wsrc1, const float* __restrict__ bsrc1,
    float* __restrict__ ws_attn, float* __restrict__ ws_out1, float* __restrict__ ws_n1m0) {
    __shared__ float sh_node[32][260];     // 32 node rows (Q*8), +4 pad   33280 B
    __shared__ float sh_src[4][256];       //                               4096 B
    __shared__ float sh_agg[4][4][256];    // also aliased as logit partials 16384 B
    __shared__ float sh_watt[4][256];      // [head][channel]                4096 B
    __shared__ float sh_attn[4][8][4];     //                                 512 B
    __shared__ float sh_logit[4][8][4];    //                                 512 B

    int tid = threadIdx.x;
    int b = blockIdx.y;
    int m0 = blockIdx.x * 4;
    int Qn = (MM - m0 < 4) ? (MM - m0) : 4;

    // stage w_att transposed: global [c][h] -> LDS [h][c]
    {
        float4 wv = *(const float4*)(watt + (size_t)tid * 4);
        sh_watt[0][tid] = wv.x; sh_watt[1][tid] = wv.y;
        sh_watt[2][tid] = wv.z; sh_watt[3][tid] = wv.w;
    }
    // node rows: x[b, m0*8+1 .. m0*8+Qn*8, :]  (contiguous slab)
    {
        const float4* gp = (const float4*)(x + ((size_t)b * LL + (size_t)m0 * 8 + 1) * CCH);
        for (int i = tid; i < Qn * 512; i += 256) {
            int row = i >> 6, c = (i & 63) * 4;
            *(float4*)&sh_node[row][c] = gp[i];
        }
    }
    // src rows: x[b, m0+q, :]
    {
        int q = tid >> 6, j = tid & 63;
        if (q < Qn) {
            const float4* sp = (const float4*)(x + ((size_t)b * LL + m0 + q) * CCH);
            *(float4*)&sh_src[q][j * 4] = sp[j];
        }
    }
    __syncthreads();

    // logits partials: thread=(q,n,jj); jj covers 32 interleaved channels, 4 heads
    float* sh_part = &sh_agg[0][0][0];     // [ (q*8+n)*8+jj ][4]
    {
        int q = tid >> 6, n = (tid >> 3) & 7, jj = tid & 7;
        float a[4] = {0.f, 0.f, 0.f, 0.f};
        const float* nr = &sh_node[q * 8 + n][0];
        const float* sr = &sh_src[q][0];
        #pragma unroll
        for (int k = 0; k < 8; ++k) {
            int c = k * 32 + jj * 4;
            float4 nv = *(const float4*)&nr[c];
            float4 sv = *(const float4*)&sr[c];
            float ft0 = nv.x + sv.x, ft1 = nv.y + sv.y;
            float ft2 = nv.z + sv.z, ft3 = nv.w + sv.w;
            #pragma unroll
            for (int h = 0; h < 4; ++h) {
                const float* wr = &sh_watt[h][c];
                a[h] = fmaf(ft0, wr[0], a[h]);
                a[h] = fmaf(ft1, wr[1], a[h]);
                a[h] = fmaf(ft2, wr[2], a[h]);
                a[h] = fmaf(ft3, wr[3], a[h]);
            }
        }
        float* pp = &sh_part[((q * 8 + n) * 8 + jj) * 4];
        pp[0] = a[0]; pp[1] = a[1]; pp[2] = a[2]; pp[3] = a[3];
    }
    __syncthreads();
    // combine partials -> logits
    if (tid < 128) {
        int q = tid >> 5, n = (tid >> 2) & 7, h = tid & 3;
        float s = batt[h];
        #pragma unroll
        for (int jj = 0; jj < 8; ++jj) s += sh_part[((q * 8 + n) * 8 + jj) * 4 + h];
        sh_logit[q][n][h] = s;
    }
    __syncthreads();
    // softmax over the 8 nodes per (q,h)
    if (tid < 16) {
        int q = tid >> 2, h = tid & 3;
        float l[8], mx = -3.0e38f;
        #pragma unroll
        for (int n = 0; n < 8; ++n) { l[n] = sh_logit[q][n][h]; mx = fmaxf(mx, l[n]); }
        float s = 0.f;
        #pragma unroll
        for (int n = 0; n < 8; ++n) { l[n] = __expf(l[n] - mx); s += l[n]; }
        float inv = 1.f / s;
        int m = m0 + q;
        bool st = (q < Qn) && (m < MM2);
        #pragma unroll
        for (int n = 0; n < 8; ++n) {
            float a = l[n] * inv;
            sh_attn[q][n][h] = a;
            if (st) ws_attn[(((size_t)b * MM2 + m) * 8 + n) * 4 + h] = a;
        }
    }
    __syncthreads();
    // agg[q][t][c] = node[2t][c]*attn[2t][h] + node[2t+1][c]*attn[2t+1][h]
    for (int i = tid; i < Qn * 256; i += 256) {
        int q = i >> 8, r = i & 255;
        int t = r >> 6, c0 = (r & 63) * 4;
        int h = c0 >> 6;
        float a0 = sh_attn[q][2 * t][h], a1 = sh_attn[q][2 * t + 1][h];
        float4 n0 = *(const float4*)&sh_node[q * 8 + 2 * t][c0];
        float4 n1 = *(const float4*)&sh_node[q * 8 + 2 * t + 1][c0];
        float4 rr;
        rr.x = n0.x * a0 + n1.x * a1; rr.y = n0.y * a0 + n1.y * a1;
        rr.z = n0.z * a0 + n1.z * a1; rr.w = n0.w * a0 + n1.w * a1;
        *(float4*)&sh_agg[q][t][c0] = rr;
    }
    __syncthreads();

    // grouped conv: thread = output channel o; agg reads are wave-uniform broadcasts
    int o = tid, g = o >> 6;
    float accn[4], accs[4];
    {
        float bn = bagg1[o], bs = bsrc1[o];
        #pragma unroll
        for (int q = 0; q < 4; ++q) { accn[q] = bn; accs[q] = bs; }
    }
    {
        const float4* wrow = (const float4*)(wt1 + (size_t)o * 256);
        for (int kk = 0; kk < 64; ++kk) {
            float4 wv = wrow[kk];
            int t = kk >> 4, ci0 = (kk & 15) * 4;
            const float* ab = &sh_agg[0][t][g * 64 + ci0];
            #pragma unroll
            for (int q = 0; q < 4; ++q) {
                float4 av = *(const float4*)(ab + q * 1024);
                accn[q] = fmaf(av.x, wv.x, accn[q]);
                accn[q] = fmaf(av.y, wv.y, accn[q]);
                accn[q] = fmaf(av.z, wv.z, accn[q]);
                accn[q] = fmaf(av.w, wv.w, accn[q]);
            }
        }
    }
    {
        const float4* srow = (const float4*)(wsrc1 + (size_t)o * 64);
        #pragma unroll
        for (int kk = 0; kk < 16; ++kk) {
            float4 wv = srow[kk];
            int ci0 = kk * 4;
            #pragma unroll
            for (int q = 0; q < 4; ++q) {
                float4 sv = *(const float4*)&sh_src[q][g * 64 + ci0];
                accs[q] = fmaf(sv.x, wv.x, accs[q]);
                accs[q] = fmaf(sv.y, wv.y, accs[q]);
                accs[q] = fmaf(sv.z, wv.z, accs[q]);
                accs[q] = fmaf(sv.w, wv.w, accs[q]);
            }
        }
    }
    #pragma unroll
    for (int q = 0; q < 4; ++q) {
        if (q < Qn) {
            int m = m0 + q;
            float n1 = fmaxf(accn[q], 0.f);
            float s1 = fmaxf(accs[q], 0.f);
            ws_out1[((size_t)b * MM + m) * CCH + o] = n1 + s1;
            if (m == 0) ws_n1m0[b * 256 + o] = n1;
        }
    }
}

// ---------- score1 ----------
__global__ __launch_bounds__(256) void score1_k(const float* __restrict__ gt1,
                                                const float* __restrict__ n1m0,
                                                float* __restrict__ score1p) {
    int b = blockIdx.x, tid = threadIdx.x;
    __shared__ float red[4];
    float d = gt1[(size_t)b * MM2 * 256 + tid] - n1m0[b * 256 + tid];
    float v = d * d;
    #pragma unroll
    for (int off = 32; off > 0; off >>= 1) v += __shfl_down(v, off, 64);
    if ((tid & 63) == 0) red[tid >> 6] = v;
    __syncthreads();
    if (tid == 0) {
        float s = red[0] + red[1] + red[2] + red[3];
        score1p[b] = 1.f - __expf(-0.5f * s);
    }
}

// ---------- Layer 2: agg + grouped conv + score2, Q=4 positions/block ----------
__global__ __launch_bounds__(256) void layer2_k(
    const float* __restrict__ out1, const float* __restrict__ ws_attn,
    const float* __restrict__ gt2,
    const float* __restrict__ wt2, const float* __restrict__ bagg2,
    const float* __restrict__ wsrc2, const float* __restrict__ bsrc2,
    float* __restrict__ outp, float* __restrict__ score2p) {
    __shared__ float sh_node[32][260];
    __shared__ float sh_src[4][256];
    __shared__ float sh_agg[4][4][256];
    __shared__ float sh_attn[4][8][4];
    __shared__ float sh_red[4][4];

    int tid = threadIdx.x;
    int b = blockIdx.y;
    int m0 = blockIdx.x * 4;

    {
        const float4* gp = (const float4*)(out1 + ((size_t)b * MM + (size_t)m0 * 8 + 1) * CCH);
        for (int i = tid; i < 2048; i += 256) {
            int row = i >> 6, c = (i & 63) * 4;
            *(float4*)&sh_node[row][c] = gp[i];
        }
    }
    {
        int q = tid >> 6, j = tid & 63;
        const float4* sp = (const float4*)(out1 + ((size_t)b * MM + m0 + q) * CCH);
        *(float4*)&sh_src[q][j * 4] = sp[j];
    }
    if (tid < 128) ((float*)sh_attn)[tid] = ws_attn[((size_t)b * MM2 + m0) * 32 + tid];
    __syncthreads();

    for (int i = tid; i < 1024; i += 256) {
        int q = i >> 8, r = i & 255;
        int t = r >> 6, c0 = (r & 63) * 4;
        int h = c0 >> 6;
        float a0 = sh_attn[q][2 * t][h], a1 = sh_attn[q][2 * t + 1][h];
        float4 n0 = *(const float4*)&sh_node[q * 8 + 2 * t][c0];
        float4 n1 = *(const float4*)&sh_node[q * 8 + 2 * t + 1][c0];
        float4 rr;
        rr.x = n0.x * a0 + n1.x * a1; rr.y = n0.y * a0 + n1.y * a1;
        rr.z = n0.z * a0 + n1.z * a1; rr.w = n0.w * a0 + n1.w * a1;
        *(float4*)&sh_agg[q][t][c0] = rr;
    }
    __syncthreads();

    int o = tid, g = o >> 6;
    float accn[4], accs[4];
    {
        float bn = bagg2[o], bs = bsrc2[o];
        #pragma unroll
        for (int q = 0; q < 4; ++q) { accn[q] = bn; accs[q] = bs; }
    }
    {
        const float4* wrow = (const float4*)(wt2 + (size_t)o * 256);
        for (int kk = 0; kk < 64; ++kk) {
            float4 wv = wrow[kk];
            int t = kk >> 4, ci0 = (kk & 15) * 4;
            const float* ab = &sh_agg[0][t][g * 64 + ci0];
            #pragma unroll
            for (int q = 0; q < 4; ++q) {
                float4 av = *(const float4*)(ab + q * 1024);
                accn[q] = fmaf(av.x, wv.x, accn[q]);
                accn[q] = fmaf(av.y, wv.y, accn[q]);
                accn[q] = fmaf(av.z, wv.z, accn[q]);
                accn[q] = fmaf(av.w, wv.w, accn[q]);
            }
        }
    }
    {
        const float4* srow = (const float4*)(wsrc2 + (size_t)o * 64);
        #pragma unroll
        for (int kk = 0; kk < 16; ++kk) {
            float4 wv = srow[kk];
            int ci0 = kk * 4;
            #pragma unroll
            for (int q = 0; q < 4; ++q) {
                float4 sv = *(const float4*)&sh_src[q][g * 64 + ci0];
                accs[q] = fmaf(sv.x, wv.x, accs[q]);
                accs[q] = fmaf(sv.y, wv.y, accs[q]);
                accs[q] = fmaf(sv.z, wv.z, accs[q]);
                accs[q] = fmaf(sv.w, wv.w, accs[q]);
            }
        }
    }
    int wid = tid >> 6, lane = tid & 63;
    #pragma unroll
    for (int q = 0; q < 4; ++q) {
        int m = m0 + q;
        size_t row = (size_t)b * MM2 + m;
        float n2 = fmaxf(accn[q], 0.f);
        float s2 = fmaxf(accs[q], 0.f);
        outp[row * 256 + o] = n2 + s2;
        float d = gt2[row * 256 + o] - n2;
        float v = d * d;
        #pragma unroll
        for (int off = 32; off > 0; off >>= 1) v += __shfl_down(v, off, 64);
        if (lane == 0) sh_red[q][wid] = v;
    }
    __syncthreads();
    if (tid < 4) {
        float s = sh_red[tid][0] + sh_red[tid][1] + sh_red[tid][2] + sh_red[tid][3];
        score2p[(size_t)b * MM2 + m0 + tid] = 1.f - __expf(-0.5f * s);
    }
}

extern "C" void kernel_launch(void* const* d_in, const int* in_sizes, int n_in,
                              void* d_out, int out_size, void* d_ws, size_t ws_size,
                              hipStream_t stream) {
    const float* x     = (const float*)d_in[0];
    const float* gt    = (const float*)d_in[1];
    const float* watt  = (const float*)d_in[2];
    const float* batt  = (const float*)d_in[3];
    const float* wgt1  = (const float*)d_in[4];
    const float* bgt1  = (const float*)d_in[5];
    const float* wgt2  = (const float*)d_in[6];
    const float* bgt2  = (const float*)d_in[7];
    const float* wagg1 = (const float*)d_in[8];
    const float* bagg1 = (const float*)d_in[9];
    const float* wsrc1 = (const float*)d_in[10];
    const float* bsrc1 = (const float*)d_in[11];
    const float* wagg2 = (const float*)d_in[12];
    const float* bagg2 = (const float*)d_in[13];
    const float* wsrc2 = (const float*)d_in[14];
    const float* bsrc2 = (const float*)d_in[15];

    char* ws = (char*)d_ws;
    float* ws_gt1   = (float*)(ws + 0);          // 2048*256 f32 = 2 MB
    float* ws_gt2   = (float*)(ws + 2097152);    // 2 MB
    float* ws_attn  = (float*)(ws + 4194304);    // 4*512*32 f32 = 256 KB
    float* ws_n1m0  = (float*)(ws + 4456448);    // 4 KB
    float* wt1      = (float*)(ws + 4460544);    // 256 KB
    float* wt2      = (float*)(ws + 4722688);    // 256 KB
    float* ws_out1  = (float*)(ws + 4984832);    // 4*4097*256 f32 = 16 MB

    float* outp    = (float*)d_out;              // 2048*256
    float* score1p = outp + 524288;              // 4
    float* score2p = outp + 524292;              // 2048

    prep_wt<<<dim3(512), dim3(256), 0, stream>>>(wagg1, wagg2, wt1, wt2);
    gemm_relu_k<<<dim3(128), dim3(256), 0, stream>>>(gt, wgt1, bgt1, ws_gt1);
    gemm_relu_k<<<dim3(128), dim3(256), 0, stream>>>(ws_gt1, wgt2, bgt2, ws_gt2);
    layer1_k<<<dim3(1025, 4), dim3(256), 0, stream>>>(x, watt, batt, wt1, bagg1, wsrc1, bsrc1,
                                                      ws_attn, ws_out1, ws_n1m0);
    score1_k<<<dim3(4), dim3(256), 0, stream>>>(ws_gt1, ws_n1m0, score1p);
    layer2_k<<<dim3(128, 4), dim3(256), 0, stream>>>(ws_out1, ws_attn, ws_gt2, wt2, bagg2,
                                                     wsrc2, bsrc2, outp, score2p);
}

// Round 3
// 338.198 us; speedup vs baseline: 1.6227x; 1.6227x over previous
//
#include <hip/hip_runtime.h>

typedef unsigned short u16;
typedef unsigned int   u32;
typedef __attribute__((ext_vector_type(8))) short short8;
typedef __attribute__((ext_vector_type(4))) float f32x4;

#define BB  4
#define LL  32777
#define MM  4097
#define MMP 4112
#define MM2 512

__device__ __forceinline__ float b2f(u16 u) { return __uint_as_float(((u32)u) << 16); }
__device__ __forceinline__ float bflo(u32 u) { return __uint_as_float(u << 16); }
__device__ __forceinline__ float bfhi(u32 u) { return __uint_as_float(u & 0xffff0000u); }
__device__ __forceinline__ u16 f2bf(float f) {
    u32 u = __float_as_uint(f);
    return (u16)((u + 0x7fffu + ((u >> 16) & 1u)) >> 16);   // RNE
}
__device__ __forceinline__ u32 pk(float a, float b) {
    return (u32)f2bf(a) | ((u32)f2bf(b) << 16);
}

// ---------- prep: swizzle conv weights fp32 -> bf16 MFMA A-fragment order ----------
// wA layout: [((g*8+kc)*4+mt)*512 + lane*8 + j], value = w[g*64+mt*16+(lane&15)][ci][t],
//            k = kc*32+(lane>>4)*8+j, t=k>>6, ci=k&63.
// wS layout: [((g*2+kc)*4+mt)*512 + lane*8 + j], k<64, value = wsrc[o][k].
__global__ __launch_bounds__(256) void prep_w(const float* __restrict__ wagg1,
                                              const float* __restrict__ wagg2,
                                              const float* __restrict__ wsrc1,
                                              const float* __restrict__ wsrc2,
                                              u16* __restrict__ wA1, u16* __restrict__ wA2,
                                              u16* __restrict__ wS1, u16* __restrict__ wS2) {
    int idx = blockIdx.x * 256 + threadIdx.x;      // 0..163839
    if (idx < 131072) {
        int which = idx >> 16;
        int e = idx & 65535;
        int j = e & 7, lane = (e >> 3) & 63, mt = (e >> 9) & 3, kc = (e >> 11) & 7, g = (e >> 14) & 3;
        int ol = mt * 16 + (lane & 15);
        int k = kc * 32 + (lane >> 4) * 8 + j;
        int t = k >> 6, ci = k & 63;
        const float* src = which ? wagg2 : wagg1;
        u16* dst = which ? wA2 : wA1;
        dst[e] = f2bf(src[(g * 64 + ol) * 256 + ci * 4 + t]);
    } else {
        int e2 = idx - 131072;
        int which = e2 >> 14;
        int e = e2 & 16383;
        int j = e & 7, lane = (e >> 3) & 63, mt = (e >> 9) & 3, kc = (e >> 11) & 1, g = (e >> 12) & 3;
        int ol = mt * 16 + (lane & 15);
        int k = kc * 32 + (lane >> 4) * 8 + j;
        const float* src = which ? wsrc2 : wsrc1;
        u16* dst = which ? wS2 : wS1;
        dst[e] = f2bf(src[(g * 64 + ol) * 64 + k]);
    }
}

// ---------- GEMM: C(2048x256) = relu(A @ W + b), fp32 ----------
__global__ __launch_bounds__(256) void gemm_relu_k(const float* __restrict__ A,
                                                   const float* __restrict__ W,
                                                   const float* __restrict__ bias,
                                                   float* __restrict__ C) {
    __shared__ float sh_at[256][16];
    int tid = threadIdx.x;
    int row0 = blockIdx.x * 16;
    {
        int r = tid >> 4, j = tid & 15;
        const float4* a4 = (const float4*)(A + (size_t)(row0 + r) * 256 + j * 16);
        #pragma unroll
        for (int kk = 0; kk < 4; ++kk) {
            float4 v = a4[kk];
            sh_at[j * 16 + kk * 4 + 0][r] = v.x;
            sh_at[j * 16 + kk * 4 + 1][r] = v.y;
            sh_at[j * 16 + kk * 4 + 2][r] = v.z;
            sh_at[j * 16 + kk * 4 + 3][r] = v.w;
        }
    }
    __syncthreads();
    int o = tid;
    float bo = bias[o];
    float acc[16];
    #pragma unroll
    for (int i = 0; i < 16; ++i) acc[i] = bo;
    #pragma unroll 4
    for (int k = 0; k < 256; ++k) {
        float w = W[k * 256 + o];
        const float4* ap = (const float4*)&sh_at[k][0];
        float4 a0 = ap[0], a1 = ap[1], a2 = ap[2], a3 = ap[3];
        acc[0]  = fmaf(a0.x, w, acc[0]);  acc[1]  = fmaf(a0.y, w, acc[1]);
        acc[2]  = fmaf(a0.z, w, acc[2]);  acc[3]  = fmaf(a0.w, w, acc[3]);
        acc[4]  = fmaf(a1.x, w, acc[4]);  acc[5]  = fmaf(a1.y, w, acc[5]);
        acc[6]  = fmaf(a1.z, w, acc[6]);  acc[7]  = fmaf(a1.w, w, acc[7]);
        acc[8]  = fmaf(a2.x, w, acc[8]);  acc[9]  = fmaf(a2.y, w, acc[9]);
        acc[10] = fmaf(a2.z, w, acc[10]); acc[11] = fmaf(a2.w, w, acc[11]);
        acc[12] = fmaf(a3.x, w, acc[12]); acc[13] = fmaf(a3.y, w, acc[13]);
        acc[14] = fmaf(a3.z, w, acc[14]); acc[15] = fmaf(a3.w, w, acc[15]);
    }
    float* cp = C + (size_t)row0 * 256 + o;
    #pragma unroll
    for (int i = 0; i < 16; ++i) cp[i * 256] = fmaxf(acc[i], 0.f);
}

// ---------- attention: logits + softmax for all m, store attnf[b][m][n*4+h] ----------
__global__ __launch_bounds__(256) void attn_k(const float* __restrict__ x,
                                              const float* __restrict__ watt,
                                              const float* __restrict__ batt,
                                              float* __restrict__ attnf) {
    __shared__ float4 sh_wattT[256];     // [c] -> w_att[c][0..3]
    __shared__ float4 sh_part[256];      // [(q*8+n)*2+jj] -> 4 head partials
    __shared__ float  sh_logit[16][8][4];

    int tid = threadIdx.x;
    int b = blockIdx.y;
    int p0 = blockIdx.x * 16;

    sh_wattT[tid] = ((const float4*)watt)[tid];
    __syncthreads();

    // phase A: partial logits. thread = (q, n, jj); jj covers 128 channels
    {
        int q = tid >> 4, n = (tid >> 1) & 7, jj = tid & 1;
        int gp = p0 + q;
        int gpc = gp < MM ? gp : (MM - 1);
        const float4* nr4 = (const float4*)(x + ((size_t)b * LL + 1 + 8 * (size_t)gpc + n) * 256 + jj * 128);
        const float4* sr4 = (const float4*)(x + ((size_t)b * LL + gpc) * 256 + jj * 128);
        float4 a = {0.f, 0.f, 0.f, 0.f};
        #pragma unroll 4
        for (int v = 0; v < 32; ++v) {
            float4 nv = nr4[v], sv = sr4[v];
            int c = jj * 128 + v * 4;
            float4 w0 = sh_wattT[c], w1 = sh_wattT[c + 1], w2 = sh_wattT[c + 2], w3 = sh_wattT[c + 3];
            float f0 = nv.x + sv.x, f1 = nv.y + sv.y, f2 = nv.z + sv.z, f3 = nv.w + sv.w;
            a.x = fmaf(f0, w0.x, a.x); a.y = fmaf(f0, w0.y, a.y);
            a.z = fmaf(f0, w0.z, a.z); a.w = fmaf(f0, w0.w, a.w);
            a.x = fmaf(f1, w1.x, a.x); a.y = fmaf(f1, w1.y, a.y);
            a.z = fmaf(f1, w1.z, a.z); a.w = fmaf(f1, w1.w, a.w);
            a.x = fmaf(f2, w2.x, a.x); a.y = fmaf(f2, w2.y, a.y);
            a.z = fmaf(f2, w2.z, a.z); a.w = fmaf(f2, w2.w, a.w);
            a.x = fmaf(f3, w3.x, a.x); a.y = fmaf(f3, w3.y, a.y);
            a.z = fmaf(f3, w3.z, a.z); a.w = fmaf(f3, w3.w, a.w);
        }
        sh_part[(q * 8 + n) * 2 + jj] = a;
    }
    __syncthreads();
    // phase B: combine partials -> logits
    #pragma unroll
    for (int rep = 0; rep < 2; ++rep) {
        int idx = tid + rep * 256;
        int qq = idx >> 5, nn = (idx >> 2) & 7, hh = idx & 3;
        int row = (qq * 8 + nn) * 2;
        float s = ((const float*)&sh_part[row])[hh] + ((const float*)&sh_part[row + 1])[hh] + batt[hh];
        sh_logit[qq][nn][hh] = s;
    }
    __syncthreads();
    // phase C: softmax over 8 nodes per (q,h); store
    if (tid < 64) {
        int q = tid >> 2, h = tid & 3;
        int gp = p0 + q;
        float l[8], mx = -3.0e38f;
        #pragma unroll
        for (int n = 0; n < 8; ++n) { l[n] = sh_logit[q][n][h]; mx = fmaxf(mx, l[n]); }
        float s = 0.f;
        #pragma unroll
        for (int n = 0; n < 8; ++n) { l[n] = __expf(l[n] - mx); s += l[n]; }
        float inv = 1.f / s;
        if (gp < MM) {
            float* ap = attnf + ((size_t)b * MMP + gp) * 32;
            #pragma unroll
            for (int n = 0; n < 8; ++n) ap[n * 4 + h] = l[n] * inv;
        }
    }
}

// ---------- layer1 conv: build bf16 agg tile in LDS, MFMA, epilogue ----------
__global__ __launch_bounds__(256) void l1conv_k(
    const float* __restrict__ x, const float* __restrict__ attnf,
    const u16* __restrict__ wA1, const u16* __restrict__ wS1,
    const float* __restrict__ bagg1, const float* __restrict__ bsrc1,
    u16* __restrict__ out1, float* __restrict__ n1m0) {
    __shared__ u16 sh_agg[16 * 1024];    // [pos][g*256 + t*64 + ci]; aliased as out tile

    int tid = threadIdx.x;
    int b = blockIdx.y;
    int p0 = blockIdx.x * 16;

    // phase 2: build agg tile (bf16)
    {
        int pos = tid >> 4, cc = tid & 15;
        int gp = p0 + pos;
        int gpc = gp < MM ? gp : (MM - 1);
        int c0 = cc * 16;
        int h = c0 >> 6;
        const float* arow = attnf + ((size_t)b * MMP + gpc) * 32;
        const float* xb = x + (size_t)b * LL * 256;
        #pragma unroll
        for (int t = 0; t < 4; ++t) {
            float a0 = arow[(2 * t) * 4 + h];
            float a1 = arow[(2 * t + 1) * 4 + h];
            const float4* r0 = (const float4*)(xb + (size_t)(1 + 8 * gpc + 2 * t) * 256 + c0);
            const float4* r1 = (const float4*)(xb + (size_t)(2 + 8 * gpc + 2 * t) * 256 + c0);
            u32 w[8];
            #pragma unroll
            for (int v = 0; v < 4; ++v) {
                float4 n0 = r0[v], n1 = r1[v];
                float4 rr;
                rr.x = fmaf(n0.x, a0, n1.x * a1); rr.y = fmaf(n0.y, a0, n1.y * a1);
                rr.z = fmaf(n0.z, a0, n1.z * a1); rr.w = fmaf(n0.w, a0, n1.w * a1);
                w[v * 2 + 0] = pk(rr.x, rr.y);
                w[v * 2 + 1] = pk(rr.z, rr.w);
            }
            u32* dst = (u32*)&sh_agg[pos * 1024 + h * 256 + t * 64 + (c0 & 63)];
            ((uint4*)dst)[0] = make_uint4(w[0], w[1], w[2], w[3]);
            ((uint4*)dst)[1] = make_uint4(w[4], w[5], w[6], w[7]);
        }
    }
    __syncthreads();

    // phase 3: MFMA. wave = group g.
    int lane = tid & 63, g = tid >> 6;
    int col = lane & 15, quad = lane >> 4;
    f32x4 accn[4], accs[4];
    #pragma unroll
    for (int mt = 0; mt < 4; ++mt) { accn[mt] = (f32x4){0,0,0,0}; accs[mt] = (f32x4){0,0,0,0}; }

    #pragma unroll
    for (int kc = 0; kc < 8; ++kc) {
        short8 bB = *(const short8*)&sh_agg[col * 1024 + g * 256 + kc * 32 + quad * 8];
        #pragma unroll
        for (int mt = 0; mt < 4; ++mt) {
            short8 aA = *(const short8*)(wA1 + (((g * 8 + kc) * 4 + mt) * 512 + lane * 8));
            accn[mt] = __builtin_amdgcn_mfma_f32_16x16x32_bf16(aA, bB, accn[mt], 0, 0, 0);
        }
    }
    #pragma unroll
    for (int kc = 0; kc < 2; ++kc) {
        const float4* sp = (const float4*)(x + ((size_t)b * LL + p0 + col) * 256 + g * 64 + kc * 32 + quad * 8);
        float4 s0 = sp[0], s1 = sp[1];
        short8 bS;
        bS[0] = (short)f2bf(s0.x); bS[1] = (short)f2bf(s0.y);
        bS[2] = (short)f2bf(s0.z); bS[3] = (short)f2bf(s0.w);
        bS[4] = (short)f2bf(s1.x); bS[5] = (short)f2bf(s1.y);
        bS[6] = (short)f2bf(s1.z); bS[7] = (short)f2bf(s1.w);
        #pragma unroll
        for (int mt = 0; mt < 4; ++mt) {
            short8 aS = *(const short8*)(wS1 + (((g * 2 + kc) * 4 + mt) * 512 + lane * 8));
            accs[mt] = __builtin_amdgcn_mfma_f32_16x16x32_bf16(aS, bS, accs[mt], 0, 0, 0);
        }
    }
    __syncthreads();   // all agg reads done; reuse LDS as out tile

    // epilogue: bias + relu + add, bf16 out tile [col][o] stride 264
    u16* outt = sh_agg;
    #pragma unroll
    for (int mt = 0; mt < 4; ++mt) {
        float v[4], n1v[4];
        #pragma unroll
        for (int r = 0; r < 4; ++r) {
            int o = g * 64 + mt * 16 + quad * 4 + r;
            float n1 = fmaxf(accn[mt][r] + bagg1[o], 0.f);
            float s1 = fmaxf(accs[mt][r] + bsrc1[o], 0.f);
            n1v[r] = n1;
            v[r] = n1 + s1;
        }
        int ob = g * 64 + mt * 16 + quad * 4;
        u32* wp = (u32*)&outt[col * 264 + ob];
        wp[0] = pk(v[0], v[1]);
        wp[1] = pk(v[2], v[3]);
        if (blockIdx.x == 0 && col == 0) {
            #pragma unroll
            for (int r = 0; r < 4; ++r) n1m0[b * 256 + ob + r] = n1v[r];
        }
    }
    __syncthreads();
    for (int j = tid; j < 512; j += 256) {
        int pos = j >> 5, cc = (j & 31) * 8;
        if (p0 + pos < MM)
            *(uint4*)&out1[((size_t)b * MMP + p0 + pos) * 256 + cc] = *(const uint4*)&outt[pos * 264 + cc];
    }
}

// ---------- score1 ----------
__global__ __launch_bounds__(256) void score1_k(const float* __restrict__ gt1,
                                                const float* __restrict__ n1m0,
                                                float* __restrict__ score1p) {
    int b = blockIdx.x, tid = threadIdx.x;
    __shared__ float red[4];
    float d = gt1[(size_t)b * MM2 * 256 + tid] - n1m0[b * 256 + tid];
    float v = d * d;
    #pragma unroll
    for (int off = 32; off > 0; off >>= 1) v += __shfl_down(v, off, 64);
    if ((tid & 63) == 0) red[tid >> 6] = v;
    __syncthreads();
    if (tid == 0) score1p[b] = 1.f - __expf(-0.5f * (red[0] + red[1] + red[2] + red[3]));
}

// ---------- layer2 conv + score2 ----------
__global__ __launch_bounds__(256) void l2conv_k(
    const u16* __restrict__ out1, const float* __restrict__ attnf,
    const float* __restrict__ gt2,
    const u16* __restrict__ wA2, const u16* __restrict__ wS2,
    const float* __restrict__ bagg2, const float* __restrict__ bsrc2,
    float* __restrict__ outp, float* __restrict__ score2p) {
    __shared__ char shraw[16 * 268 * 4 * 2];    // agg tile (32KB) / out+n2 tiles (fp32)
    __shared__ float shred[256];

    int tid = threadIdx.x;
    int b = blockIdx.y;
    int p0 = blockIdx.x * 16;
    u16* aggl = (u16*)shraw;

    // phase 2: build agg2 tile from out1 (bf16) + attn
    {
        int pos = tid >> 4, cc = tid & 15;
        int m = p0 + pos;
        int c0 = cc * 16;
        int h = c0 >> 6;
        const float* arow = attnf + ((size_t)b * MMP + m) * 32;
        #pragma unroll
        for (int t = 0; t < 4; ++t) {
            float a0 = arow[(2 * t) * 4 + h];
            float a1 = arow[(2 * t + 1) * 4 + h];
            const uint4* r0 = (const uint4*)(out1 + ((size_t)b * MMP + 1 + 8 * m + 2 * t) * 256 + c0);
            const uint4* r1 = (const uint4*)(out1 + ((size_t)b * MMP + 2 + 8 * m + 2 * t) * 256 + c0);
            u32 w[8];
            #pragma unroll
            for (int v = 0; v < 2; ++v) {
                uint4 p = r0[v], q = r1[v];
                u32 pv[4] = {p.x, p.y, p.z, p.w};
                u32 qv[4] = {q.x, q.y, q.z, q.w};
                #pragma unroll
                for (int e = 0; e < 4; ++e) {
                    float lo = fmaf(bflo(pv[e]), a0, bflo(qv[e]) * a1);
                    float hi = fmaf(bfhi(pv[e]), a0, bfhi(qv[e]) * a1);
                    w[v * 4 + e] = pk(lo, hi);
                }
            }
            u32* dst = (u32*)&aggl[pos * 1024 + h * 256 + t * 64 + (c0 & 63)];
            ((uint4*)dst)[0] = make_uint4(w[0], w[1], w[2], w[3]);
            ((uint4*)dst)[1] = make_uint4(w[4], w[5], w[6], w[7]);
        }
    }
    __syncthreads();

    int lane = tid & 63, g = tid >> 6;
    int col = lane & 15, quad = lane >> 4;
    f32x4 accn[4], accs[4];
    #pragma unroll
    for (int mt = 0; mt < 4; ++mt) { accn[mt] = (f32x4){0,0,0,0}; accs[mt] = (f32x4){0,0,0,0}; }

    #pragma unroll
    for (int kc = 0; kc < 8; ++kc) {
        short8 bB = *(const short8*)&aggl[col * 1024 + g * 256 + kc * 32 + quad * 8];
        #pragma unroll
        for (int mt = 0; mt < 4; ++mt) {
            short8 aA = *(const short8*)(wA2 + (((g * 8 + kc) * 4 + mt) * 512 + lane * 8));
            accn[mt] = __builtin_amdgcn_mfma_f32_16x16x32_bf16(aA, bB, accn[mt], 0, 0, 0);
        }
    }
    #pragma unroll
    for (int kc = 0; kc < 2; ++kc) {
        short8 bS = *(const short8*)(out1 + ((size_t)b * MMP + p0 + col) * 256 + g * 64 + kc * 32 + quad * 8);
        #pragma unroll
        for (int mt = 0; mt < 4; ++mt) {
            short8 aS = *(const short8*)(wS2 + (((g * 2 + kc) * 4 + mt) * 512 + lane * 8));
            accs[mt] = __builtin_amdgcn_mfma_f32_16x16x32_bf16(aS, bS, accs[mt], 0, 0, 0);
        }
    }
    __syncthreads();

    // epilogue: fp32 out + n2 tiles, stride 268
    float* outt = (float*)shraw;
    float* n2t  = outt + 16 * 268;
    #pragma unroll
    for (int mt = 0; mt < 4; ++mt) {
        #pragma unroll
        for (int r = 0; r < 4; ++r) {
            int o = g * 64 + mt * 16 + quad * 4 + r;
            float n2 = fmaxf(accn[mt][r] + bagg2[o], 0.f);
            float s2 = fmaxf(accs[mt][r] + bsrc2[o], 0.f);
            outt[col * 268 + o] = n2 + s2;
            n2t[col * 268 + o] = n2;
        }
    }
    __syncthreads();

    // final output store (coalesced)
    for (int j = tid; j < 1024; j += 256) {
        int pos = j >> 6, cc = (j & 63) * 4;
        *(float4*)&outp[((size_t)b * MM2 + p0 + pos) * 256 + cc] = *(const float4*)&outt[pos * 268 + cc];
    }
    // score2 reduction
    {
        int pos = tid >> 4, kk = tid & 15;
        const float* grow = gt2 + ((size_t)b * MM2 + p0 + pos) * 256 + kk * 16;
        const float* nrow = n2t + pos * 268 + kk * 16;
        float s = 0.f;
        #pragma unroll
        for (int c = 0; c < 16; ++c) { float d = grow[c] - nrow[c]; s = fmaf(d, d, s); }
        shred[pos * 16 + kk] = s;
    }
    __syncthreads();
    if (tid < 16) {
        float s = 0.f;
        #pragma unroll
        for (int kk = 0; kk < 16; ++kk) s += shred[tid * 16 + kk];
        score2p[(size_t)b * MM2 + p0 + tid] = 1.f - __expf(-0.5f * s);
    }
}

extern "C" void kernel_launch(void* const* d_in, const int* in_sizes, int n_in,
                              void* d_out, int out_size, void* d_ws, size_t ws_size,
                              hipStream_t stream) {
    const float* x     = (const float*)d_in[0];
    const float* gt    = (const float*)d_in[1];
    const float* watt  = (const float*)d_in[2];
    const float* batt  = (const float*)d_in[3];
    const float* wgt1  = (const float*)d_in[4];
    const float* bgt1  = (const float*)d_in[5];
    const float* wgt2  = (const float*)d_in[6];
    const float* bgt2  = (const float*)d_in[7];
    const float* wagg1 = (const float*)d_in[8];
    const float* bagg1 = (const float*)d_in[9];
    const float* wsrc1 = (const float*)d_in[10];
    const float* bsrc1 = (const float*)d_in[11];
    const float* wagg2 = (const float*)d_in[12];
    const float* bagg2 = (const float*)d_in[13];
    const float* wsrc2 = (const float*)d_in[14];
    const float* bsrc2 = (const float*)d_in[15];

    char* ws = (char*)d_ws;
    float* ws_gt1  = (float*)(ws + 0);            // 2 MB
    float* ws_gt2  = (float*)(ws + 2097152);      // 2 MB
    float* attnf   = (float*)(ws + 4194304);      // 4*4112*32 f32 = 2,105,344 B
    float* n1m0    = (float*)(ws + 6299648);      // 4 KB
    u16*   wA1     = (u16*)(ws + 6303744);        // 128 KB
    u16*   wS1     = (u16*)(ws + 6434816);        // 32 KB
    u16*   wA2     = (u16*)(ws + 6467584);        // 128 KB
    u16*   wS2     = (u16*)(ws + 6598656);        // 32 KB
    u16*   out1    = (u16*)(ws + 6631424);        // 4*4112*256 bf16 = 8,421,376 B

    float* outp    = (float*)d_out;               // 2048*256
    float* score1p = outp + 524288;               // 4
    float* score2p = outp + 524292;               // 2048

    prep_w<<<dim3(640), dim3(256), 0, stream>>>(wagg1, wagg2, wsrc1, wsrc2, wA1, wA2, wS1, wS2);
    gemm_relu_k<<<dim3(128), dim3(256), 0, stream>>>(gt, wgt1, bgt1, ws_gt1);
    gemm_relu_k<<<dim3(128), dim3(256), 0, stream>>>(ws_gt1, wgt2, bgt2, ws_gt2);
    attn_k<<<dim3(257, 4), dim3(256), 0, stream>>>(x, watt, batt, attnf);
    l1conv_k<<<dim3(257, 4), dim3(256), 0, stream>>>(x, attnf, wA1, wS1, bagg1, bsrc1, out1, n1m0);
    score1_k<<<dim3(4), dim3(256), 0, stream>>>(ws_gt1, n1m0, score1p);
    l2conv_k<<<dim3(32, 4), dim3(256), 0, stream>>>(out1, attnf, ws_gt2, wA2, wS2, bagg2, bsrc2,
                                                    outp, score2p);
}

// Round 4
// 311.230 us; speedup vs baseline: 1.7633x; 1.0867x over previous
//
#include <hip/hip_runtime.h>

typedef unsigned short u16;
typedef unsigned int   u32;
typedef __attribute__((ext_vector_type(8))) short short8;
typedef __attribute__((ext_vector_type(4))) float f32x4;

#define BB  4
#define LL  32777
#define MM  4097
#define MMP 4112
#define MM2 512

__device__ __forceinline__ float b2f(u16 u) { return __uint_as_float(((u32)u) << 16); }
__device__ __forceinline__ u16 f2bf(float f) {
    u32 u = __float_as_uint(f);
    return (u16)((u + 0x7fffu + ((u >> 16) & 1u)) >> 16);   // RNE
}
__device__ __forceinline__ u32 pk(float a, float b) {
    return (u32)f2bf(a) | ((u32)f2bf(b) << 16);
}
__device__ __forceinline__ float bflo(u32 u) { return __uint_as_float(u << 16); }
__device__ __forceinline__ float bfhi(u32 u) { return __uint_as_float(u & 0xffff0000u); }

// ---------- prep: swizzle conv weights fp32 -> bf16 MFMA A-fragment order ----------
__global__ __launch_bounds__(256) void prep_w(const float* __restrict__ wagg1,
                                              const float* __restrict__ wagg2,
                                              const float* __restrict__ wsrc1,
                                              const float* __restrict__ wsrc2,
                                              u16* __restrict__ wA1, u16* __restrict__ wA2,
                                              u16* __restrict__ wS1, u16* __restrict__ wS2) {
    int idx = blockIdx.x * 256 + threadIdx.x;      // 0..163839
    if (idx < 131072) {
        int which = idx >> 16;
        int e = idx & 65535;
        int j = e & 7, lane = (e >> 3) & 63, mt = (e >> 9) & 3, kc = (e >> 11) & 7, g = (e >> 14) & 3;
        int ol = mt * 16 + (lane & 15);
        int k = kc * 32 + (lane >> 4) * 8 + j;
        int t = k >> 6, ci = k & 63;
        const float* src = which ? wagg2 : wagg1;
        u16* dst = which ? wA2 : wA1;
        dst[e] = f2bf(src[(g * 64 + ol) * 256 + ci * 4 + t]);
    } else {
        int e2 = idx - 131072;
        int which = e2 >> 14;
        int e = e2 & 16383;
        int j = e & 7, lane = (e >> 3) & 63, mt = (e >> 9) & 3, kc = (e >> 11) & 1, g = (e >> 12) & 3;
        int ol = mt * 16 + (lane & 15);
        int k = kc * 32 + (lane >> 4) * 8 + j;
        const float* src = which ? wsrc2 : wsrc1;
        u16* dst = which ? wS2 : wS1;
        dst[e] = f2bf(src[(g * 64 + ol) * 64 + k]);
    }
}

// ---------- fused GEMM: gt1 = relu(gt@W1+b1) in LDS, gt2 = relu(gt1@W2+b2) ----------
__global__ __launch_bounds__(256) void gemm2_fused_k(
    const float* __restrict__ gt, const float* __restrict__ W1, const float* __restrict__ b1,
    const float* __restrict__ W2, const float* __restrict__ b2,
    float* __restrict__ gt2, float* __restrict__ gt1m0) {
    __shared__ float sh[256][8];
    int tid = threadIdx.x;
    int row0 = blockIdx.x * 8;
    {
        int r = tid >> 5, j = tid & 31;
        const float4* a4 = (const float4*)(gt + (size_t)(row0 + r) * 256 + j * 8);
        float4 v0 = a4[0], v1 = a4[1];
        sh[j * 8 + 0][r] = v0.x; sh[j * 8 + 1][r] = v0.y;
        sh[j * 8 + 2][r] = v0.z; sh[j * 8 + 3][r] = v0.w;
        sh[j * 8 + 4][r] = v1.x; sh[j * 8 + 5][r] = v1.y;
        sh[j * 8 + 6][r] = v1.z; sh[j * 8 + 7][r] = v1.w;
    }
    __syncthreads();
    int o = tid;
    float acc[8];
    {
        float bo = b1[o];
        #pragma unroll
        for (int i = 0; i < 8; ++i) acc[i] = bo;
    }
    #pragma unroll 4
    for (int k = 0; k < 256; ++k) {
        float wv = W1[k * 256 + o];
        const float4* ap = (const float4*)&sh[k][0];
        float4 a0 = ap[0], a1 = ap[1];
        acc[0] = fmaf(a0.x, wv, acc[0]); acc[1] = fmaf(a0.y, wv, acc[1]);
        acc[2] = fmaf(a0.z, wv, acc[2]); acc[3] = fmaf(a0.w, wv, acc[3]);
        acc[4] = fmaf(a1.x, wv, acc[4]); acc[5] = fmaf(a1.y, wv, acc[5]);
        acc[6] = fmaf(a1.z, wv, acc[6]); acc[7] = fmaf(a1.w, wv, acc[7]);
    }
    #pragma unroll
    for (int i = 0; i < 8; ++i) acc[i] = fmaxf(acc[i], 0.f);
    if ((row0 & 511) == 0) gt1m0[(row0 >> 9) * 256 + o] = acc[0];
    __syncthreads();
    #pragma unroll
    for (int i = 0; i < 8; ++i) sh[o][i] = acc[i];
    __syncthreads();
    {
        float bo = b2[o];
        #pragma unroll
        for (int i = 0; i < 8; ++i) acc[i] = bo;
    }
    #pragma unroll 4
    for (int k = 0; k < 256; ++k) {
        float wv = W2[k * 256 + o];
        const float4* ap = (const float4*)&sh[k][0];
        float4 a0 = ap[0], a1 = ap[1];
        acc[0] = fmaf(a0.x, wv, acc[0]); acc[1] = fmaf(a0.y, wv, acc[1]);
        acc[2] = fmaf(a0.z, wv, acc[2]); acc[3] = fmaf(a0.w, wv, acc[3]);
        acc[4] = fmaf(a1.x, wv, acc[4]); acc[5] = fmaf(a1.y, wv, acc[5]);
        acc[6] = fmaf(a1.z, wv, acc[6]); acc[7] = fmaf(a1.w, wv, acc[7]);
    }
    #pragma unroll
    for (int i = 0; i < 8; ++i) gt2[(size_t)(row0 + i) * 256 + o] = fmaxf(acc[i], 0.f);
}

// ---------- fused layer1: stage x once -> logits -> softmax -> MFMA conv ----------
// LDS = 65536 (node slab bf16, swizzled) + 8192 (src bf16) + 8192 (scratch) = 81920 B -> 2 blk/CU
__global__ __launch_bounds__(256, 2) void l1fused_k(
    const float* __restrict__ x, const float* __restrict__ watt, const float* __restrict__ batt,
    const u16* __restrict__ wA1, const u16* __restrict__ wS1,
    const float* __restrict__ bagg1, const float* __restrict__ bsrc1,
    float* __restrict__ attnf, u16* __restrict__ out1, float* __restrict__ n1m0) {
    __shared__ u16   sh_node[128 * 256];   // [r][cb^((r>>3 ^ r)&7)] bf16
    __shared__ u16   sh_srcq[16 * 256];    // [q][cb^(q&7)] bf16; aliased as out tile
    __shared__ float shR[2048];            // phaseA: wattT[0..1023]+partials[1024..2047];
                                           // then: logits[0..511], attn[512..1023]

    int tid = threadIdx.x;
    int lane = tid & 63, w = tid >> 6;
    int b = blockIdx.y;
    int p0 = blockIdx.x * 16;

    // stage w_att: shR[0..1023] as float4 per channel
    ((float4*)shR)[tid] = ((const float4*)watt)[tid];

    // stage x slab (coalesced: 16 lanes cover one contiguous 1KB row)
    {
        int cseg = lane & 15;
        int rsub = lane >> 4;
        const float* xb = x + (size_t)b * LL * 256;
        #pragma unroll
        for (int i = 0; i < 9; ++i) {
            int r = (w * 9 + i) * 4 + rsub;          // 0..143
            int grow, key; u16* dst;
            if (r < 128) {
                int pos = r >> 3, nn = r & 7;
                int gp = p0 + pos; int gpc = gp < MM ? gp : MM - 1;
                grow = 1 + 8 * gpc + nn;
                dst = sh_node + r * 256;
                key = ((r >> 3) ^ r) & 7;
            } else {
                int q = r - 128;
                int gp = p0 + q; int gpc = gp < MM ? gp : MM - 1;
                grow = gpc;
                dst = sh_srcq + q * 256;
                key = q & 7;
            }
            const float4* src4 = (const float4*)(xb + (size_t)grow * 256 + cseg * 16);
            float4 v0 = src4[0], v1 = src4[1], v2 = src4[2], v3 = src4[3];
            uint4 o0, o1;
            o0.x = pk(v0.x, v0.y); o0.y = pk(v0.z, v0.w);
            o0.z = pk(v1.x, v1.y); o0.w = pk(v1.z, v1.w);
            o1.x = pk(v2.x, v2.y); o1.y = pk(v2.z, v2.w);
            o1.z = pk(v3.x, v3.y); o1.w = pk(v3.z, v3.w);
            int cb0 = cseg * 2;
            *(uint4*)(dst + ((cb0 ^ key) * 8))       = o0;
            *(uint4*)(dst + (((cb0 + 1) ^ key) * 8)) = o1;
        }
    }
    __syncthreads();

    // phase A: partial logits. thread = (q, n, jj); jj covers 128 channels, 4 heads
    {
        int q = tid >> 4, n = (tid >> 1) & 7, jj = tid & 1;
        int nkey = (q ^ n) & 7;
        int skey = q & 7;
        const u16* nr = sh_node + (q * 8 + n) * 256;
        const u16* sr = sh_srcq + q * 256;
        const float4* wT = (const float4*)shR;
        float4 a = {0.f, 0.f, 0.f, 0.f};
        #pragma unroll 4
        for (int v = 0; v < 16; ++v) {
            int cb = jj * 16 + v;
            short8 nv = *(const short8*)(nr + ((cb ^ nkey) * 8));
            short8 sv = *(const short8*)(sr + ((cb ^ skey) * 8));
            int c0 = cb * 8;
            #pragma unroll
            for (int j = 0; j < 8; ++j) {
                float ft = b2f((u16)nv[j]) + b2f((u16)sv[j]);
                float4 wv = wT[c0 + j];
                a.x = fmaf(ft, wv.x, a.x); a.y = fmaf(ft, wv.y, a.y);
                a.z = fmaf(ft, wv.z, a.z); a.w = fmaf(ft, wv.w, a.w);
            }
        }
        ((float4*)(shR + 1024))[(q * 8 + n) * 2 + jj] = a;
    }
    __syncthreads();
    // combine partials -> logits (shR[0..511], layout [q][n][h])
    {
        const float* part = shR + 1024;
        #pragma unroll
        for (int rep = 0; rep < 2; ++rep) {
            int idx = tid + rep * 256;
            int qq = idx >> 5, nn = (idx >> 2) & 7, hh = idx & 3;
            int row = (qq * 8 + nn) * 2;
            shR[idx] = part[row * 4 + hh] + part[(row + 1) * 4 + hh] + batt[hh];
        }
    }
    __syncthreads();
    // softmax over 8 nodes per (q,h); attn -> shR[512..1023] layout [n][h][16]
    if (tid < 64) {
        int q = tid >> 2, h = tid & 3;
        float l[8], mx = -3.0e38f;
        #pragma unroll
        for (int n = 0; n < 8; ++n) { l[n] = shR[(q * 8 + n) * 4 + h]; mx = fmaxf(mx, l[n]); }
        float s = 0.f;
        #pragma unroll
        for (int n = 0; n < 8; ++n) { l[n] = __expf(l[n] - mx); s += l[n]; }
        float inv = 1.f / s;
        int gp = p0 + q;
        float* at = shR + 512;
        #pragma unroll
        for (int n = 0; n < 8; ++n) {
            float aa = l[n] * inv;
            at[(n * 4 + h) * 16 + q] = aa;
            if (gp < MM2) attnf[(((size_t)b * MM2 + gp) * 8 + n) * 4 + h] = aa;
        }
    }
    __syncthreads();

    // MFMA phase: wave = group g; B-fragments built in registers from node slab
    int g = w;
    int col = lane & 15, quad = lane >> 4;
    float aT[8];
    {
        const float* at = shR + 512;
        #pragma unroll
        for (int nn = 0; nn < 8; ++nn) aT[nn] = at[(nn * 4 + g) * 16 + col];
    }
    f32x4 accn[4], accs[4];
    #pragma unroll
    for (int mt = 0; mt < 4; ++mt) { accn[mt] = (f32x4){0,0,0,0}; accs[mt] = (f32x4){0,0,0,0}; }

    #pragma unroll
    for (int kc = 0; kc < 8; ++kc) {
        int k0 = kc * 32 + quad * 8;
        int t = k0 >> 6, ci0 = k0 & 63;
        int cb = (g * 64 + ci0) >> 3;
        int r0 = col * 8 + 2 * t;
        int key0 = (col ^ (2 * t)) & 7, key1 = (col ^ (2 * t + 1)) & 7;
        short8 n0 = *(const short8*)(sh_node + r0 * 256 + ((cb ^ key0) * 8));
        short8 n1 = *(const short8*)(sh_node + (r0 + 1) * 256 + ((cb ^ key1) * 8));
        float a0 = aT[2 * t], a1 = aT[2 * t + 1];
        union { uint4 u; short8 s; } cv;
        #pragma unroll
        for (int e = 0; e < 4; ++e) {
            float lo = fmaf(a0, b2f((u16)n0[2 * e]),     a1 * b2f((u16)n1[2 * e]));
            float hi = fmaf(a0, b2f((u16)n0[2 * e + 1]), a1 * b2f((u16)n1[2 * e + 1]));
            ((u32*)&cv.u)[e] = pk(lo, hi);
        }
        short8 bB = cv.s;
        #pragma unroll
        for (int mt = 0; mt < 4; ++mt) {
            short8 aA = *(const short8*)(wA1 + (((g * 8 + kc) * 4 + mt) * 512 + lane * 8));
            accn[mt] = __builtin_amdgcn_mfma_f32_16x16x32_bf16(aA, bB, accn[mt], 0, 0, 0);
        }
    }
    #pragma unroll
    for (int kc = 0; kc < 2; ++kc) {
        int cb = (g * 64 + kc * 32 + quad * 8) >> 3;
        short8 bS = *(const short8*)(sh_srcq + col * 256 + ((cb ^ (col & 7)) * 8));
        #pragma unroll
        for (int mt = 0; mt < 4; ++mt) {
            short8 aS = *(const short8*)(wS1 + (((g * 2 + kc) * 4 + mt) * 512 + lane * 8));
            accs[mt] = __builtin_amdgcn_mfma_f32_16x16x32_bf16(aS, bS, accs[mt], 0, 0, 0);
        }
    }
    __syncthreads();   // src reads done; reuse sh_srcq as out tile [pos][o]

    u16* outt = sh_srcq;
    #pragma unroll
    for (int mt = 0; mt < 4; ++mt) {
        int ob = g * 64 + mt * 16 + quad * 4;
        float v[4], n1v[4];
        #pragma unroll
        for (int r = 0; r < 4; ++r) {
            int o = ob + r;
            float n1 = fmaxf(accn[mt][r] + bagg1[o], 0.f);
            float s1 = fmaxf(accs[mt][r] + bsrc1[o], 0.f);
            n1v[r] = n1;
            v[r] = n1 + s1;
        }
        u32* wp = (u32*)&outt[col * 256 + ob];
        wp[0] = pk(v[0], v[1]);
        wp[1] = pk(v[2], v[3]);
        if (blockIdx.x == 0 && col == 0) {
            #pragma unroll
            for (int r = 0; r < 4; ++r) n1m0[b * 256 + ob + r] = n1v[r];
        }
    }
    __syncthreads();
    for (int j = tid; j < 512; j += 256) {
        int pos = j >> 5, cc = (j & 31) * 8;
        if (p0 + pos < MM)
            *(uint4*)&out1[((size_t)b * MMP + p0 + pos) * 256 + cc] = *(const uint4*)&outt[pos * 256 + cc];
    }
}

// ---------- score1 ----------
__global__ __launch_bounds__(256) void score1_k(const float* __restrict__ gt1m0,
                                                const float* __restrict__ n1m0,
                                                float* __restrict__ score1p) {
    int b = blockIdx.x, tid = threadIdx.x;
    __shared__ float red[4];
    float d = gt1m0[b * 256 + tid] - n1m0[b * 256 + tid];
    float v = d * d;
    #pragma unroll
    for (int off = 32; off > 0; off >>= 1) v += __shfl_down(v, off, 64);
    if ((tid & 63) == 0) red[tid >> 6] = v;
    __syncthreads();
    if (tid == 0) score1p[b] = 1.f - __expf(-0.5f * (red[0] + red[1] + red[2] + red[3]));
}

// ---------- layer2 conv + score2 ----------
__global__ __launch_bounds__(256) void l2conv_k(
    const u16* __restrict__ out1, const float* __restrict__ attnf,
    const float* __restrict__ gt2,
    const u16* __restrict__ wA2, const u16* __restrict__ wS2,
    const float* __restrict__ bagg2, const float* __restrict__ bsrc2,
    float* __restrict__ outp, float* __restrict__ score2p) {
    __shared__ char shraw[16 * 268 * 4 * 2];
    __shared__ float shred[256];

    int tid = threadIdx.x;
    int b = blockIdx.y;
    int p0 = blockIdx.x * 16;
    u16* aggl = (u16*)shraw;

    {
        int pos = tid >> 4, cc = tid & 15;
        int m = p0 + pos;
        int c0 = cc * 16;
        int h = c0 >> 6;
        const float* arow = attnf + ((size_t)b * MM2 + m) * 32;
        #pragma unroll
        for (int t = 0; t < 4; ++t) {
            float a0 = arow[(2 * t) * 4 + h];
            float a1 = arow[(2 * t + 1) * 4 + h];
            const uint4* r0 = (const uint4*)(out1 + ((size_t)b * MMP + 1 + 8 * m + 2 * t) * 256 + c0);
            const uint4* r1 = (const uint4*)(out1 + ((size_t)b * MMP + 2 + 8 * m + 2 * t) * 256 + c0);
            u32 w[8];
            #pragma unroll
            for (int v = 0; v < 2; ++v) {
                uint4 p = r0[v], q = r1[v];
                u32 pv[4] = {p.x, p.y, p.z, p.w};
                u32 qv[4] = {q.x, q.y, q.z, q.w};
                #pragma unroll
                for (int e = 0; e < 4; ++e) {
                    float lo = fmaf(bflo(pv[e]), a0, bflo(qv[e]) * a1);
                    float hi = fmaf(bfhi(pv[e]), a0, bfhi(qv[e]) * a1);
                    w[v * 4 + e] = pk(lo, hi);
                }
            }
            u32* dst = (u32*)&aggl[pos * 1024 + h * 256 + t * 64 + (c0 & 63)];
            ((uint4*)dst)[0] = make_uint4(w[0], w[1], w[2], w[3]);
            ((uint4*)dst)[1] = make_uint4(w[4], w[5], w[6], w[7]);
        }
    }
    __syncthreads();

    int lane = tid & 63, g = tid >> 6;
    int col = lane & 15, quad = lane >> 4;
    f32x4 accn[4], accs[4];
    #pragma unroll
    for (int mt = 0; mt < 4; ++mt) { accn[mt] = (f32x4){0,0,0,0}; accs[mt] = (f32x4){0,0,0,0}; }

    #pragma unroll
    for (int kc = 0; kc < 8; ++kc) {
        short8 bB = *(const short8*)&aggl[col * 1024 + g * 256 + kc * 32 + quad * 8];
        #pragma unroll
        for (int mt = 0; mt < 4; ++mt) {
            short8 aA = *(const short8*)(wA2 + (((g * 8 + kc) * 4 + mt) * 512 + lane * 8));
            accn[mt] = __builtin_amdgcn_mfma_f32_16x16x32_bf16(aA, bB, accn[mt], 0, 0, 0);
        }
    }
    #pragma unroll
    for (int kc = 0; kc < 2; ++kc) {
        short8 bS = *(const short8*)(out1 + ((size_t)b * MMP + p0 + col) * 256 + g * 64 + kc * 32 + quad * 8);
        #pragma unroll
        for (int mt = 0; mt < 4; ++mt) {
            short8 aS = *(const short8*)(wS2 + (((g * 2 + kc) * 4 + mt) * 512 + lane * 8));
            accs[mt] = __builtin_amdgcn_mfma_f32_16x16x32_bf16(aS, bS, accs[mt], 0, 0, 0);
        }
    }
    __syncthreads();

    float* outt = (float*)shraw;
    float* n2t  = outt + 16 * 268;
    #pragma unroll
    for (int mt = 0; mt < 4; ++mt) {
        #pragma unroll
        for (int r = 0; r < 4; ++r) {
            int o = g * 64 + mt * 16 + quad * 4 + r;
            float n2 = fmaxf(accn[mt][r] + bagg2[o], 0.f);
            float s2 = fmaxf(accs[mt][r] + bsrc2[o], 0.f);
            outt[col * 268 + o] = n2 + s2;
            n2t[col * 268 + o] = n2;
        }
    }
    __syncthreads();

    for (int j = tid; j < 1024; j += 256) {
        int pos = j >> 6, cc = (j & 63) * 4;
        *(float4*)&outp[((size_t)b * MM2 + p0 + pos) * 256 + cc] = *(const float4*)&outt[pos * 268 + cc];
    }
    {
        int pos = tid >> 4, kk = tid & 15;
        const float* grow = gt2 + ((size_t)b * MM2 + p0 + pos) * 256 + kk * 16;
        const float* nrow = n2t + pos * 268 + kk * 16;
        float s = 0.f;
        #pragma unroll
        for (int c = 0; c < 16; ++c) { float d = grow[c] - nrow[c]; s = fmaf(d, d, s); }
        shred[pos * 16 + kk] = s;
    }
    __syncthreads();
    if (tid < 16) {
        float s = 0.f;
        #pragma unroll
        for (int kk = 0; kk < 16; ++kk) s += shred[tid * 16 + kk];
        score2p[(size_t)b * MM2 + p0 + tid] = 1.f - __expf(-0.5f * s);
    }
}

extern "C" void kernel_launch(void* const* d_in, const int* in_sizes, int n_in,
                              void* d_out, int out_size, void* d_ws, size_t ws_size,
                              hipStream_t stream) {
    const float* x     = (const float*)d_in[0];
    const float* gt    = (const float*)d_in[1];
    const float* watt  = (const float*)d_in[2];
    const float* batt  = (const float*)d_in[3];
    const float* wgt1  = (const float*)d_in[4];
    const float* bgt1  = (const float*)d_in[5];
    const float* wgt2  = (const float*)d_in[6];
    const float* bgt2  = (const float*)d_in[7];
    const float* wagg1 = (const float*)d_in[8];
    const float* bagg1 = (const float*)d_in[9];
    const float* wsrc1 = (const float*)d_in[10];
    const float* bsrc1 = (const float*)d_in[11];
    const float* wagg2 = (const float*)d_in[12];
    const float* bagg2 = (const float*)d_in[13];
    const float* wsrc2 = (const float*)d_in[14];
    const float* bsrc2 = (const float*)d_in[15];

    char* ws = (char*)d_ws;
    float* ws_gt2  = (float*)(ws + 0);            // 2 MB
    float* attnf   = (float*)(ws + 2097152);      // 4*512*32 f32 = 256 KB
    float* n1m0    = (float*)(ws + 2359296);      // 4 KB
    float* gt1m0   = (float*)(ws + 2363392);      // 4 KB
    u16*   wA1     = (u16*)(ws + 2367488);        // 128 KB
    u16*   wS1     = (u16*)(ws + 2498560);        // 32 KB
    u16*   wA2     = (u16*)(ws + 2531328);        // 128 KB
    u16*   wS2     = (u16*)(ws + 2662400);        // 32 KB
    u16*   out1    = (u16*)(ws + 2695168);        // 4*4112*256 bf16 = 8,421,376 B

    float* outp    = (float*)d_out;               // 2048*256
    float* score1p = outp + 524288;               // 4
    float* score2p = outp + 524292;               // 2048

    prep_w<<<dim3(640), dim3(256), 0, stream>>>(wagg1, wagg2, wsrc1, wsrc2, wA1, wA2, wS1, wS2);
    gemm2_fused_k<<<dim3(256), dim3(256), 0, stream>>>(gt, wgt1, bgt1, wgt2, bgt2, ws_gt2, gt1m0);
    l1fused_k<<<dim3(257, 4), dim3(256), 0, stream>>>(x, watt, batt, wA1, wS1, bagg1, bsrc1,
                                                      attnf, out1, n1m0);
    score1_k<<<dim3(4), dim3(256), 0, stream>>>(gt1m0, n1m0, score1p);
    l2conv_k<<<dim3(32, 4), dim3(256), 0, stream>>>(out1, attnf, ws_gt2, wA2, wS2, bagg2, bsrc2,
                                                    outp, score2p);
}

// Round 5
// 307.078 us; speedup vs baseline: 1.7871x; 1.0135x over previous
//
#include <hip/hip_runtime.h>

typedef unsigned short u16;
typedef unsigned int   u32;
typedef __attribute__((ext_vector_type(8))) short short8;
typedef __attribute__((ext_vector_type(4))) float f32x4;

#define BB  4
#define LL  32777
#define MM  4097
#define MMP 4112
#define MM2 512

__device__ __forceinline__ float b2f(u16 u) { return __uint_as_float(((u32)u) << 16); }
__device__ __forceinline__ u16 f2bf(float f) {
    u32 u = __float_as_uint(f);
    return (u16)((u + 0x7fffu + ((u >> 16) & 1u)) >> 16);   // RNE
}
__device__ __forceinline__ u32 pk(float a, float b) {
    return (u32)f2bf(a) | ((u32)f2bf(b) << 16);
}
__device__ __forceinline__ float bflo(u32 u) { return __uint_as_float(u << 16); }
__device__ __forceinline__ float bfhi(u32 u) { return __uint_as_float(u & 0xffff0000u); }

// ---------- prep: swizzle weights fp32 -> bf16 MFMA fragment orders ----------
// wA: A-frag for conv GEMM.  wS: A-frag for src conv.  wattB: B-frag of w_att
// (B[k][n]: n=lane&15 -> head (0 for n>=4), k=kc*32+(lane>>4)*8+j).
__global__ __launch_bounds__(256) void prep_w(const float* __restrict__ wagg1,
                                              const float* __restrict__ wagg2,
                                              const float* __restrict__ wsrc1,
                                              const float* __restrict__ wsrc2,
                                              const float* __restrict__ watt,
                                              u16* __restrict__ wA1, u16* __restrict__ wA2,
                                              u16* __restrict__ wS1, u16* __restrict__ wS2,
                                              u16* __restrict__ wattB) {
    int idx = blockIdx.x * 256 + threadIdx.x;      // 0..167935
    if (idx < 131072) {
        int which = idx >> 16;
        int e = idx & 65535;
        int j = e & 7, lane = (e >> 3) & 63, mt = (e >> 9) & 3, kc = (e >> 11) & 7, g = (e >> 14) & 3;
        int ol = mt * 16 + (lane & 15);
        int k = kc * 32 + (lane >> 4) * 8 + j;
        int t = k >> 6, ci = k & 63;
        const float* src = which ? wagg2 : wagg1;
        u16* dst = which ? wA2 : wA1;
        dst[e] = f2bf(src[(g * 64 + ol) * 256 + ci * 4 + t]);
    } else if (idx < 163840) {
        int e2 = idx - 131072;
        int which = e2 >> 14;
        int e = e2 & 16383;
        int j = e & 7, lane = (e >> 3) & 63, mt = (e >> 9) & 3, kc = (e >> 11) & 1, g = (e >> 12) & 3;
        int ol = mt * 16 + (lane & 15);
        int k = kc * 32 + (lane >> 4) * 8 + j;
        const float* src = which ? wsrc2 : wsrc1;
        u16* dst = which ? wS2 : wS1;
        dst[e] = f2bf(src[(g * 64 + ol) * 64 + k]);
    } else if (idx < 167936) {
        int e = idx - 163840;                      // 0..4095
        int j = e & 7, lane = (e >> 3) & 63, kc = e >> 9;
        int h = lane & 15, quad = lane >> 4;
        int k = kc * 32 + quad * 8 + j;
        wattB[e] = (h < 4) ? f2bf(watt[k * 4 + h]) : (u16)0;
    }
}

// ---------- fused GEMM: gt1 = relu(gt@W1+b1) in LDS, gt2 = relu(gt1@W2+b2) ----------
__global__ __launch_bounds__(256) void gemm2_fused_k(
    const float* __restrict__ gt, const float* __restrict__ W1, const float* __restrict__ b1,
    const float* __restrict__ W2, const float* __restrict__ b2,
    float* __restrict__ gt2, float* __restrict__ gt1m0) {
    __shared__ float sh[256][8];
    int tid = threadIdx.x;
    int row0 = blockIdx.x * 8;
    {
        int r = tid >> 5, j = tid & 31;
        const float4* a4 = (const float4*)(gt + (size_t)(row0 + r) * 256 + j * 8);
        float4 v0 = a4[0], v1 = a4[1];
        sh[j * 8 + 0][r] = v0.x; sh[j * 8 + 1][r] = v0.y;
        sh[j * 8 + 2][r] = v0.z; sh[j * 8 + 3][r] = v0.w;
        sh[j * 8 + 4][r] = v1.x; sh[j * 8 + 5][r] = v1.y;
        sh[j * 8 + 6][r] = v1.z; sh[j * 8 + 7][r] = v1.w;
    }
    __syncthreads();
    int o = tid;
    float acc[8];
    {
        float bo = b1[o];
        #pragma unroll
        for (int i = 0; i < 8; ++i) acc[i] = bo;
    }
    #pragma unroll 4
    for (int k = 0; k < 256; ++k) {
        float wv = W1[k * 256 + o];
        const float4* ap = (const float4*)&sh[k][0];
        float4 a0 = ap[0], a1 = ap[1];
        acc[0] = fmaf(a0.x, wv, acc[0]); acc[1] = fmaf(a0.y, wv, acc[1]);
        acc[2] = fmaf(a0.z, wv, acc[2]); acc[3] = fmaf(a0.w, wv, acc[3]);
        acc[4] = fmaf(a1.x, wv, acc[4]); acc[5] = fmaf(a1.y, wv, acc[5]);
        acc[6] = fmaf(a1.z, wv, acc[6]); acc[7] = fmaf(a1.w, wv, acc[7]);
    }
    #pragma unroll
    for (int i = 0; i < 8; ++i) acc[i] = fmaxf(acc[i], 0.f);
    if ((row0 & 511) == 0) gt1m0[(row0 >> 9) * 256 + o] = acc[0];
    __syncthreads();
    #pragma unroll
    for (int i = 0; i < 8; ++i) sh[o][i] = acc[i];
    __syncthreads();
    {
        float bo = b2[o];
        #pragma unroll
        for (int i = 0; i < 8; ++i) acc[i] = bo;
    }
    #pragma unroll 4
    for (int k = 0; k < 256; ++k) {
        float wv = W2[k * 256 + o];
        const float4* ap = (const float4*)&sh[k][0];
        float4 a0 = ap[0], a1 = ap[1];
        acc[0] = fmaf(a0.x, wv, acc[0]); acc[1] = fmaf(a0.y, wv, acc[1]);
        acc[2] = fmaf(a0.z, wv, acc[2]); acc[3] = fmaf(a0.w, wv, acc[3]);
        acc[4] = fmaf(a1.x, wv, acc[4]); acc[5] = fmaf(a1.y, wv, acc[5]);
        acc[6] = fmaf(a1.z, wv, acc[6]); acc[7] = fmaf(a1.w, wv, acc[7]);
    }
    #pragma unroll
    for (int i = 0; i < 8; ++i) gt2[(size_t)(row0 + i) * 256 + o] = fmaxf(acc[i], 0.f);
}

// ---------- fused layer1: stage x -> MFMA logits -> softmax -> MFMA conv ----------
// LDS = 65536 (node slab) + 8192 (src) + 4352 (rowdots/attn) = 78080 B -> 2 blk/CU
__global__ __launch_bounds__(256, 2) void l1fused_k(
    const float* __restrict__ x, const float* __restrict__ batt,
    const u16* __restrict__ wA1, const u16* __restrict__ wS1,
    const u16* __restrict__ wattB,
    const float* __restrict__ bagg1, const float* __restrict__ bsrc1,
    float* __restrict__ attnf, u16* __restrict__ out1, float* __restrict__ n1m0) {
    __shared__ u16   sh_node[128 * 256];   // [r][cb^((r>>3 ^ r)&7)] bf16
    __shared__ u16   sh_srcq[16 * 256];    // [q][cb^(q&7)] bf16; aliased as out tile
    __shared__ float shR[1088];            // rdN[0..511], rdS[512..575], attn[576..1087]

    int tid = threadIdx.x;
    int lane = tid & 63, w = tid >> 6;
    int quad = lane >> 4;
    int b = blockIdx.y;
    int p0 = blockIdx.x * 16;

    // stage x slab (coalesced: 16 lanes cover one contiguous 1KB row)
    {
        int cseg = lane & 15;
        int rsub = lane >> 4;
        const float* xb = x + (size_t)b * LL * 256;
        #pragma unroll
        for (int i = 0; i < 9; ++i) {
            int r = (w * 9 + i) * 4 + rsub;          // 0..143
            int grow, key; u16* dst;
            if (r < 128) {
                int pos = r >> 3, nn = r & 7;
                int gp = p0 + pos; int gpc = gp < MM ? gp : MM - 1;
                grow = 1 + 8 * gpc + nn;
                dst = sh_node + r * 256;
                key = ((r >> 3) ^ r) & 7;
            } else {
                int q = r - 128;
                int gp = p0 + q; int gpc = gp < MM ? gp : MM - 1;
                grow = gpc;
                dst = sh_srcq + q * 256;
                key = q & 7;
            }
            const float4* src4 = (const float4*)(xb + (size_t)grow * 256 + cseg * 16);
            float4 v0 = src4[0], v1 = src4[1], v2 = src4[2], v3 = src4[3];
            uint4 o0, o1;
            o0.x = pk(v0.x, v0.y); o0.y = pk(v0.z, v0.w);
            o0.z = pk(v1.x, v1.y); o0.w = pk(v1.z, v1.w);
            o1.x = pk(v2.x, v2.y); o1.y = pk(v2.z, v2.w);
            o1.z = pk(v3.x, v3.y); o1.w = pk(v3.z, v3.w);
            int cb0 = cseg * 2;
            *(uint4*)(dst + ((cb0 ^ key) * 8))       = o0;
            *(uint4*)(dst + (((cb0 + 1) ^ key) * 8)) = o1;
        }
    }
    __syncthreads();

    // phase 1: rowdots via MFMA. wave w: node m-tiles {2w, 2w+1}; wave 3 also src.
    {
        short8 wB[8];
        #pragma unroll
        for (int kc = 0; kc < 8; ++kc) wB[kc] = *(const short8*)(wattB + kc * 512 + lane * 8);
        int m = lane & 15;            // A-frag row within tile
        int h = lane & 15;            // D col (head; valid < 4)
        #pragma unroll
        for (int ti = 0; ti < 2; ++ti) {
            int mt = w * 2 + ti;
            int r = mt * 16 + m;
            int key = ((r >> 3) ^ r) & 7;
            const u16* rowp = sh_node + r * 256;
            f32x4 acc = (f32x4){0.f, 0.f, 0.f, 0.f};
            #pragma unroll
            for (int kc = 0; kc < 8; ++kc) {
                int cb = kc * 4 + quad;
                short8 aF = *(const short8*)(rowp + ((cb ^ key) * 8));
                acc = __builtin_amdgcn_mfma_f32_16x16x32_bf16(aF, wB[kc], acc, 0, 0, 0);
            }
            if (h < 4) {
                #pragma unroll
                for (int r2 = 0; r2 < 4; ++r2)
                    shR[(mt * 16 + quad * 4 + r2) * 4 + h] = acc[r2];
            }
        }
        if (w == 3) {
            int key = m & 7;
            const u16* rowp = sh_srcq + m * 256;
            f32x4 acc = (f32x4){0.f, 0.f, 0.f, 0.f};
            #pragma unroll
            for (int kc = 0; kc < 8; ++kc) {
                int cb = kc * 4 + quad;
                short8 aF = *(const short8*)(rowp + ((cb ^ key) * 8));
                acc = __builtin_amdgcn_mfma_f32_16x16x32_bf16(aF, wB[kc], acc, 0, 0, 0);
            }
            if (h < 4) {
                #pragma unroll
                for (int r2 = 0; r2 < 4; ++r2)
                    shR[512 + (quad * 4 + r2) * 4 + h] = acc[r2];
            }
        }
    }
    __syncthreads();

    // phase 2: softmax over 8 nodes per (q,h); attn -> shR[576..1087] layout [n][h][16]
    if (tid < 64) {
        int q = tid >> 2, h = tid & 3;
        float base = shR[512 + q * 4 + h] + batt[h];
        float l[8], mx = -3.0e38f;
        #pragma unroll
        for (int n = 0; n < 8; ++n) { l[n] = shR[(q * 8 + n) * 4 + h] + base; mx = fmaxf(mx, l[n]); }
        float s = 0.f;
        #pragma unroll
        for (int n = 0; n < 8; ++n) { l[n] = __expf(l[n] - mx); s += l[n]; }
        float inv = 1.f / s;
        int gp = p0 + q;
        float* at = shR + 576;
        #pragma unroll
        for (int n = 0; n < 8; ++n) {
            float aa = l[n] * inv;
            at[(n * 4 + h) * 16 + q] = aa;
            if (gp < MM2) attnf[(((size_t)b * MM2 + gp) * 8 + n) * 4 + h] = aa;
        }
    }
    __syncthreads();

    // phase 3: conv MFMA. wave = group g; B-fragments built in registers.
    int g = w;
    int col = lane & 15;
    float aT[8];
    {
        const float* at = shR + 576;
        #pragma unroll
        for (int nn = 0; nn < 8; ++nn) aT[nn] = at[(nn * 4 + g) * 16 + col];
    }
    f32x4 accn[4], accs[4];
    #pragma unroll
    for (int mt = 0; mt < 4; ++mt) { accn[mt] = (f32x4){0,0,0,0}; accs[mt] = (f32x4){0,0,0,0}; }

    #pragma unroll
    for (int kc = 0; kc < 8; ++kc) {
        int k0 = kc * 32 + quad * 8;
        int t = k0 >> 6, ci0 = k0 & 63;
        int cb = (g * 64 + ci0) >> 3;
        int r0 = col * 8 + 2 * t;
        int key0 = (col ^ (2 * t)) & 7, key1 = (col ^ (2 * t + 1)) & 7;
        short8 n0 = *(const short8*)(sh_node + r0 * 256 + ((cb ^ key0) * 8));
        short8 n1 = *(const short8*)(sh_node + (r0 + 1) * 256 + ((cb ^ key1) * 8));
        float a0 = aT[2 * t], a1 = aT[2 * t + 1];
        union { uint4 u; short8 s; } cv;
        #pragma unroll
        for (int e = 0; e < 4; ++e) {
            float lo = fmaf(a0, b2f((u16)n0[2 * e]),     a1 * b2f((u16)n1[2 * e]));
            float hi = fmaf(a0, b2f((u16)n0[2 * e + 1]), a1 * b2f((u16)n1[2 * e + 1]));
            ((u32*)&cv.u)[e] = pk(lo, hi);
        }
        short8 bB = cv.s;
        #pragma unroll
        for (int mt = 0; mt < 4; ++mt) {
            short8 aA = *(const short8*)(wA1 + (((g * 8 + kc) * 4 + mt) * 512 + lane * 8));
            accn[mt] = __builtin_amdgcn_mfma_f32_16x16x32_bf16(aA, bB, accn[mt], 0, 0, 0);
        }
    }
    #pragma unroll
    for (int kc = 0; kc < 2; ++kc) {
        int cb = (g * 64 + kc * 32 + quad * 8) >> 3;
        short8 bS = *(const short8*)(sh_srcq + col * 256 + ((cb ^ (col & 7)) * 8));
        #pragma unroll
        for (int mt = 0; mt < 4; ++mt) {
            short8 aS = *(const short8*)(wS1 + (((g * 2 + kc) * 4 + mt) * 512 + lane * 8));
            accs[mt] = __builtin_amdgcn_mfma_f32_16x16x32_bf16(aS, bS, accs[mt], 0, 0, 0);
        }
    }
    __syncthreads();   // src reads done; reuse sh_srcq as out tile [pos][o]

    u16* outt = sh_srcq;
    #pragma unroll
    for (int mt = 0; mt < 4; ++mt) {
        int ob = g * 64 + mt * 16 + quad * 4;
        float v[4], n1v[4];
        #pragma unroll
        for (int r = 0; r < 4; ++r) {
            int o = ob + r;
            float n1 = fmaxf(accn[mt][r] + bagg1[o], 0.f);
            float s1 = fmaxf(accs[mt][r] + bsrc1[o], 0.f);
            n1v[r] = n1;
            v[r] = n1 + s1;
        }
        u32* wp = (u32*)&outt[col * 256 + ob];
        wp[0] = pk(v[0], v[1]);
        wp[1] = pk(v[2], v[3]);
        if (blockIdx.x == 0 && col == 0) {
            #pragma unroll
            for (int r = 0; r < 4; ++r) n1m0[b * 256 + ob + r] = n1v[r];
        }
    }
    __syncthreads();
    for (int j = tid; j < 512; j += 256) {
        int pos = j >> 5, cc = (j & 31) * 8;
        if (p0 + pos < MM)
            *(uint4*)&out1[((size_t)b * MMP + p0 + pos) * 256 + cc] = *(const uint4*)&outt[pos * 256 + cc];
    }
}

// ---------- score1 ----------
__global__ __launch_bounds__(256) void score1_k(const float* __restrict__ gt1m0,
                                                const float* __restrict__ n1m0,
                                                float* __restrict__ score1p) {
    int b = blockIdx.x, tid = threadIdx.x;
    __shared__ float red[4];
    float d = gt1m0[b * 256 + tid] - n1m0[b * 256 + tid];
    float v = d * d;
    #pragma unroll
    for (int off = 32; off > 0; off >>= 1) v += __shfl_down(v, off, 64);
    if ((tid & 63) == 0) red[tid >> 6] = v;
    __syncthreads();
    if (tid == 0) score1p[b] = 1.f - __expf(-0.5f * (red[0] + red[1] + red[2] + red[3]));
}

// ---------- layer2 conv + score2, 8 positions/block ----------
__global__ __launch_bounds__(256) void l2conv_k(
    const u16* __restrict__ out1, const float* __restrict__ attnf,
    const float* __restrict__ gt2,
    const u16* __restrict__ wA2, const u16* __restrict__ wS2,
    const float* __restrict__ bagg2, const float* __restrict__ bsrc2,
    float* __restrict__ outp, float* __restrict__ score2p) {
    __shared__ char shraw[16 * 268 * 4 * 2];
    __shared__ float shred[128];

    int tid = threadIdx.x;
    int b = blockIdx.y;
    int p0 = blockIdx.x * 8;
    u16* aggl = (u16*)shraw;

    {
        int pos16 = tid >> 4, cc = tid & 15;
        int pos = pos16 < 8 ? pos16 : 7;         // cols 8..15 duplicate pos 7
        int m = p0 + pos;
        int c0 = cc * 16;
        int h = c0 >> 6;
        const float* arow = attnf + ((size_t)b * MM2 + m) * 32;
        #pragma unroll
        for (int t = 0; t < 4; ++t) {
            float a0 = arow[(2 * t) * 4 + h];
            float a1 = arow[(2 * t + 1) * 4 + h];
            const uint4* r0 = (const uint4*)(out1 + ((size_t)b * MMP + 1 + 8 * m + 2 * t) * 256 + c0);
            const uint4* r1 = (const uint4*)(out1 + ((size_t)b * MMP + 2 + 8 * m + 2 * t) * 256 + c0);
            u32 w[8];
            #pragma unroll
            for (int v = 0; v < 2; ++v) {
                uint4 p = r0[v], q = r1[v];
                u32 pv[4] = {p.x, p.y, p.z, p.w};
                u32 qv[4] = {q.x, q.y, q.z, q.w};
                #pragma unroll
                for (int e = 0; e < 4; ++e) {
                    float lo = fmaf(bflo(pv[e]), a0, bflo(qv[e]) * a1);
                    float hi = fmaf(bfhi(pv[e]), a0, bfhi(qv[e]) * a1);
                    w[v * 4 + e] = pk(lo, hi);
                }
            }
            u32* dst = (u32*)&aggl[pos16 * 1024 + h * 256 + t * 64 + (c0 & 63)];
            ((uint4*)dst)[0] = make_uint4(w[0], w[1], w[2], w[3]);
            ((uint4*)dst)[1] = make_uint4(w[4], w[5], w[6], w[7]);
        }
    }
    __syncthreads();

    int lane = tid & 63, g = tid >> 6;
    int col = lane & 15, quad = lane >> 4;
    f32x4 accn[4], accs[4];
    #pragma unroll
    for (int mt = 0; mt < 4; ++mt) { accn[mt] = (f32x4){0,0,0,0}; accs[mt] = (f32x4){0,0,0,0}; }

    #pragma unroll
    for (int kc = 0; kc < 8; ++kc) {
        short8 bB = *(const short8*)&aggl[col * 1024 + g * 256 + kc * 32 + quad * 8];
        #pragma unroll
        for (int mt = 0; mt < 4; ++mt) {
            short8 aA = *(const short8*)(wA2 + (((g * 8 + kc) * 4 + mt) * 512 + lane * 8));
            accn[mt] = __builtin_amdgcn_mfma_f32_16x16x32_bf16(aA, bB, accn[mt], 0, 0, 0);
        }
    }
    {
        int pcol = col < 8 ? col : 7;
        #pragma unroll
        for (int kc = 0; kc < 2; ++kc) {
            short8 bS = *(const short8*)(out1 + ((size_t)b * MMP + p0 + pcol) * 256 + g * 64 + kc * 32 + quad * 8);
            #pragma unroll
            for (int mt = 0; mt < 4; ++mt) {
                short8 aS = *(const short8*)(wS2 + (((g * 2 + kc) * 4 + mt) * 512 + lane * 8));
                accs[mt] = __builtin_amdgcn_mfma_f32_16x16x32_bf16(aS, bS, accs[mt], 0, 0, 0);
            }
        }
    }
    __syncthreads();

    float* outt = (float*)shraw;
    float* n2t  = outt + 16 * 268;
    #pragma unroll
    for (int mt = 0; mt < 4; ++mt) {
        #pragma unroll
        for (int r = 0; r < 4; ++r) {
            int o = g * 64 + mt * 16 + quad * 4 + r;
            float n2 = fmaxf(accn[mt][r] + bagg2[o], 0.f);
            float s2 = fmaxf(accs[mt][r] + bsrc2[o], 0.f);
            outt[col * 268 + o] = n2 + s2;
            n2t[col * 268 + o] = n2;
        }
    }
    __syncthreads();

    for (int j = tid; j < 512; j += 256) {
        int pos = j >> 6, cc = (j & 63) * 4;
        *(float4*)&outp[((size_t)b * MM2 + p0 + pos) * 256 + cc] = *(const float4*)&outt[pos * 268 + cc];
    }
    if (tid < 128) {
        int pos = tid >> 4, kk = tid & 15;
        const float* grow = gt2 + ((size_t)b * MM2 + p0 + pos) * 256 + kk * 16;
        const float* nrow = n2t + pos * 268 + kk * 16;
        float s = 0.f;
        #pragma unroll
        for (int c = 0; c < 16; ++c) { float d = grow[c] - nrow[c]; s = fmaf(d, d, s); }
        shred[pos * 16 + kk] = s;
    }
    __syncthreads();
    if (tid < 8) {
        float s = 0.f;
        #pragma unroll
        for (int kk = 0; kk < 16; ++kk) s += shred[tid * 16 + kk];
        score2p[(size_t)b * MM2 + p0 + tid] = 1.f - __expf(-0.5f * s);
    }
}

extern "C" void kernel_launch(void* const* d_in, const int* in_sizes, int n_in,
                              void* d_out, int out_size, void* d_ws, size_t ws_size,
                              hipStream_t stream) {
    const float* x     = (const float*)d_in[0];
    const float* gt    = (const float*)d_in[1];
    const float* watt  = (const float*)d_in[2];
    const float* batt  = (const float*)d_in[3];
    const float* wgt1  = (const float*)d_in[4];
    const float* bgt1  = (const float*)d_in[5];
    const float* wgt2  = (const float*)d_in[6];
    const float* bgt2  = (const float*)d_in[7];
    const float* wagg1 = (const float*)d_in[8];
    const float* bagg1 = (const float*)d_in[9];
    const float* wsrc1 = (const float*)d_in[10];
    const float* bsrc1 = (const float*)d_in[11];
    const float* wagg2 = (const float*)d_in[12];
    const float* bagg2 = (const float*)d_in[13];
    const float* wsrc2 = (const float*)d_in[14];
    const float* bsrc2 = (const float*)d_in[15];

    char* ws = (char*)d_ws;
    float* ws_gt2  = (float*)(ws + 0);            // 2 MB
    float* attnf   = (float*)(ws + 2097152);      // 256 KB
    float* n1m0    = (float*)(ws + 2359296);      // 4 KB
    float* gt1m0   = (float*)(ws + 2363392);      // 4 KB
    u16*   wA1     = (u16*)(ws + 2367488);        // 128 KB
    u16*   wS1     = (u16*)(ws + 2498560);        // 32 KB
    u16*   wA2     = (u16*)(ws + 2531328);        // 128 KB
    u16*   wS2     = (u16*)(ws + 2662400);        // 32 KB
    u16*   wattB   = (u16*)(ws + 2695168);        // 8 KB
    u16*   out1    = (u16*)(ws + 2703360);        // 8,421,376 B

    float* outp    = (float*)d_out;               // 2048*256
    float* score1p = outp + 524288;               // 4
    float* score2p = outp + 524292;               // 2048

    prep_w<<<dim3(656), dim3(256), 0, stream>>>(wagg1, wagg2, wsrc1, wsrc2, watt,
                                                wA1, wA2, wS1, wS2, wattB);
    gemm2_fused_k<<<dim3(256), dim3(256), 0, stream>>>(gt, wgt1, bgt1, wgt2, bgt2, ws_gt2, gt1m0);
    l1fused_k<<<dim3(257, 4), dim3(256), 0, stream>>>(x, batt, wA1, wS1, wattB, bagg1, bsrc1,
                                                      attnf, out1, n1m0);
    score1_k<<<dim3(4), dim3(256), 0, stream>>>(gt1m0, n1m0, score1p);
    l2conv_k<<<dim3(64, 4), dim3(256), 0, stream>>>(out1, attnf, ws_gt2, wA2, wS2, bagg2, bsrc2,
                                                    outp, score2p);
}

// Round 6
// 300.543 us; speedup vs baseline: 1.8260x; 1.0217x over previous
//
#include <hip/hip_runtime.h>

typedef unsigned short u16;
typedef unsigned int   u32;
typedef __attribute__((ext_vector_type(8))) short short8;
typedef __attribute__((ext_vector_type(4))) float f32x4;

#define BB  4
#define LL  32777
#define MM  4097
#define MMP 4112
#define MM2 512

__device__ __forceinline__ float b2f(u16 u) { return __uint_as_float(((u32)u) << 16); }
__device__ __forceinline__ u16 f2bf(float f) {
    u32 u = __float_as_uint(f);
    return (u16)((u + 0x7fffu + ((u >> 16) & 1u)) >> 16);   // RNE
}
__device__ __forceinline__ u32 pk(float a, float b) {
    return (u32)f2bf(a) | ((u32)f2bf(b) << 16);
}
__device__ __forceinline__ float bflo(u32 u) { return __uint_as_float(u << 16); }
__device__ __forceinline__ float bfhi(u32 u) { return __uint_as_float(u & 0xffff0000u); }

// ---------- setup: weight swizzles (blocks 0..655) + fused gt GEMMs (656..911) ----------
__global__ __launch_bounds__(256) void setup_k(
    const float* __restrict__ wagg1, const float* __restrict__ wagg2,
    const float* __restrict__ wsrc1, const float* __restrict__ wsrc2,
    const float* __restrict__ watt,
    u16* __restrict__ wA1, u16* __restrict__ wA2,
    u16* __restrict__ wS1, u16* __restrict__ wS2, u16* __restrict__ wattB,
    const float* __restrict__ gt, const float* __restrict__ W1, const float* __restrict__ b1,
    const float* __restrict__ W2, const float* __restrict__ b2,
    float* __restrict__ gt2, float* __restrict__ gt1m0) {
    __shared__ float sh[256][8];
    int tid = threadIdx.x;
    if (blockIdx.x < 656) {
        int idx = blockIdx.x * 256 + tid;              // 0..167935
        if (idx < 131072) {
            int which = idx >> 16;
            int e = idx & 65535;
            int j = e & 7, lane = (e >> 3) & 63, mt = (e >> 9) & 3, kc = (e >> 11) & 7, g = (e >> 14) & 3;
            int ol = mt * 16 + (lane & 15);
            int k = kc * 32 + (lane >> 4) * 8 + j;
            int t = k >> 6, ci = k & 63;
            const float* src = which ? wagg2 : wagg1;
            u16* dst = which ? wA2 : wA1;
            dst[e] = f2bf(src[(g * 64 + ol) * 256 + ci * 4 + t]);
        } else if (idx < 163840) {
            int e2 = idx - 131072;
            int which = e2 >> 14;
            int e = e2 & 16383;
            int j = e & 7, lane = (e >> 3) & 63, mt = (e >> 9) & 3, kc = (e >> 11) & 1, g = (e >> 12) & 3;
            int ol = mt * 16 + (lane & 15);
            int k = kc * 32 + (lane >> 4) * 8 + j;
            const float* src = which ? wsrc2 : wsrc1;
            u16* dst = which ? wS2 : wS1;
            dst[e] = f2bf(src[(g * 64 + ol) * 64 + k]);
        } else {
            int e = idx - 163840;                      // 0..4095
            int j = e & 7, lane = (e >> 3) & 63, kc = e >> 9;
            int h = lane & 15, quad = lane >> 4;
            int k = kc * 32 + quad * 8 + j;
            wattB[e] = (h < 4) ? f2bf(watt[k * 4 + h]) : (u16)0;
        }
        return;
    }
    // ---- fused GEMM part ----
    int row0 = (blockIdx.x - 656) * 8;
    {
        int r = tid >> 5, j = tid & 31;
        const float4* a4 = (const float4*)(gt + (size_t)(row0 + r) * 256 + j * 8);
        float4 v0 = a4[0], v1 = a4[1];
        sh[j * 8 + 0][r] = v0.x; sh[j * 8 + 1][r] = v0.y;
        sh[j * 8 + 2][r] = v0.z; sh[j * 8 + 3][r] = v0.w;
        sh[j * 8 + 4][r] = v1.x; sh[j * 8 + 5][r] = v1.y;
        sh[j * 8 + 6][r] = v1.z; sh[j * 8 + 7][r] = v1.w;
    }
    __syncthreads();
    int o = tid;
    float acc[8];
    {
        float bo = b1[o];
        #pragma unroll
        for (int i = 0; i < 8; ++i) acc[i] = bo;
    }
    #pragma unroll 4
    for (int k = 0; k < 256; ++k) {
        float wv = W1[k * 256 + o];
        const float4* ap = (const float4*)&sh[k][0];
        float4 a0 = ap[0], a1 = ap[1];
        acc[0] = fmaf(a0.x, wv, acc[0]); acc[1] = fmaf(a0.y, wv, acc[1]);
        acc[2] = fmaf(a0.z, wv, acc[2]); acc[3] = fmaf(a0.w, wv, acc[3]);
        acc[4] = fmaf(a1.x, wv, acc[4]); acc[5] = fmaf(a1.y, wv, acc[5]);
        acc[6] = fmaf(a1.z, wv, acc[6]); acc[7] = fmaf(a1.w, wv, acc[7]);
    }
    #pragma unroll
    for (int i = 0; i < 8; ++i) acc[i] = fmaxf(acc[i], 0.f);
    if ((row0 & 511) == 0) gt1m0[(row0 >> 9) * 256 + o] = acc[0];
    __syncthreads();
    #pragma unroll
    for (int i = 0; i < 8; ++i) sh[o][i] = acc[i];
    __syncthreads();
    {
        float bo = b2[o];
        #pragma unroll
        for (int i = 0; i < 8; ++i) acc[i] = bo;
    }
    #pragma unroll 4
    for (int k = 0; k < 256; ++k) {
        float wv = W2[k * 256 + o];
        const float4* ap = (const float4*)&sh[k][0];
        float4 a0 = ap[0], a1 = ap[1];
        acc[0] = fmaf(a0.x, wv, acc[0]); acc[1] = fmaf(a0.y, wv, acc[1]);
        acc[2] = fmaf(a0.z, wv, acc[2]); acc[3] = fmaf(a0.w, wv, acc[3]);
        acc[4] = fmaf(a1.x, wv, acc[4]); acc[5] = fmaf(a1.y, wv, acc[5]);
        acc[6] = fmaf(a1.z, wv, acc[6]); acc[7] = fmaf(a1.w, wv, acc[7]);
    }
    #pragma unroll
    for (int i = 0; i < 8; ++i) gt2[(size_t)(row0 + i) * 256 + o] = fmaxf(acc[i], 0.f);
}

// ---------- fused layer1: 8 positions/block, 39.2 KB LDS -> 4 blocks/CU ----------
__global__ __launch_bounds__(256, 4) void l1fused_k(
    const float* __restrict__ x, const float* __restrict__ batt,
    const u16* __restrict__ wA1, const u16* __restrict__ wS1,
    const u16* __restrict__ wattB,
    const float* __restrict__ bagg1, const float* __restrict__ bsrc1,
    float* __restrict__ attnf, u16* __restrict__ out1, float* __restrict__ n1m0) {
    __shared__ u16   sh_node[64 * 256];    // [r=pos*8+n][cb^((pos^n)&7)] bf16, 32 KB
    __shared__ u16   sh_srcq[8 * 256];     // [q][cb^(q&7)] bf16, 4 KB; aliased as out tile
    __shared__ float shR[576];             // rdN[0..255], rdS[256..319], attn[320..575]

    int tid = threadIdx.x;
    int lane = tid & 63, w = tid >> 6;
    int quad = lane >> 4;
    int b = blockIdx.y;
    int p0 = blockIdx.x * 8;

    // stage x slab (16 lanes cover one contiguous 1KB row; 72 rows in 5 passes)
    {
        int rslot = tid >> 4, cseg = tid & 15;
        const float* xb = x + (size_t)b * LL * 256;
        #pragma unroll
        for (int pass = 0; pass < 5; ++pass) {
            int r = pass * 16 + rslot;
            if (r < 72) {
                int grow, key; u16* dst;
                if (r < 64) {
                    int pos = r >> 3, nn = r & 7;
                    int gp = p0 + pos; int gpc = gp < MM ? gp : MM - 1;
                    grow = 1 + 8 * gpc + nn;
                    dst = sh_node + r * 256;
                    key = (pos ^ nn) & 7;
                } else {
                    int q = r - 64;
                    int gp = p0 + q; int gpc = gp < MM ? gp : MM - 1;
                    grow = gpc;
                    dst = sh_srcq + q * 256;
                    key = q & 7;
                }
                const float4* src4 = (const float4*)(xb + (size_t)grow * 256 + cseg * 16);
                float4 v0 = src4[0], v1 = src4[1], v2 = src4[2], v3 = src4[3];
                uint4 o0, o1;
                o0.x = pk(v0.x, v0.y); o0.y = pk(v0.z, v0.w);
                o0.z = pk(v1.x, v1.y); o0.w = pk(v1.z, v1.w);
                o1.x = pk(v2.x, v2.y); o1.y = pk(v2.z, v2.w);
                o1.z = pk(v3.x, v3.y); o1.w = pk(v3.z, v3.w);
                int cb0 = cseg * 2;
                *(uint4*)(dst + ((cb0 ^ key) * 8))       = o0;
                *(uint4*)(dst + (((cb0 + 1) ^ key) * 8)) = o1;
            }
        }
    }
    __syncthreads();

    // phase 1: rowdots via MFMA. wave w: node m-tile w; wave 3 also src tile.
    {
        short8 wB[8];
        #pragma unroll
        for (int kc = 0; kc < 8; ++kc) wB[kc] = *(const short8*)(wattB + kc * 512 + lane * 8);
        int m = lane & 15;            // A-frag row within tile
        int h = lane & 15;            // D col (head; valid < 4)
        {
            int r = w * 16 + m;
            int key = ((r >> 3) ^ (r & 7)) & 7;
            const u16* rowp = sh_node + r * 256;
            f32x4 acc = (f32x4){0.f, 0.f, 0.f, 0.f};
            #pragma unroll
            for (int kc = 0; kc < 8; ++kc) {
                int cb = kc * 4 + quad;
                short8 aF = *(const short8*)(rowp + ((cb ^ key) * 8));
                acc = __builtin_amdgcn_mfma_f32_16x16x32_bf16(aF, wB[kc], acc, 0, 0, 0);
            }
            if (h < 4) {
                #pragma unroll
                for (int r2 = 0; r2 < 4; ++r2)
                    shR[(w * 16 + quad * 4 + r2) * 4 + h] = acc[r2];
            }
        }
        if (w == 3) {
            int ms = m < 8 ? m : 7;
            int key = ms & 7;
            const u16* rowp = sh_srcq + ms * 256;
            f32x4 acc = (f32x4){0.f, 0.f, 0.f, 0.f};
            #pragma unroll
            for (int kc = 0; kc < 8; ++kc) {
                int cb = kc * 4 + quad;
                short8 aF = *(const short8*)(rowp + ((cb ^ key) * 8));
                acc = __builtin_amdgcn_mfma_f32_16x16x32_bf16(aF, wB[kc], acc, 0, 0, 0);
            }
            if (h < 4) {
                #pragma unroll
                for (int r2 = 0; r2 < 4; ++r2) {
                    int rr = quad * 4 + r2;
                    if (rr < 8) shR[256 + rr * 4 + h] = acc[r2];
                }
            }
        }
    }
    __syncthreads();

    // phase 2: softmax over 8 nodes per (q,h); attn -> shR[320..575] layout [n][h][8]
    if (tid < 32) {
        int q = tid >> 2, h = tid & 3;
        float base = shR[256 + q * 4 + h] + batt[h];
        float l[8], mx = -3.0e38f;
        #pragma unroll
        for (int n = 0; n < 8; ++n) { l[n] = shR[(q * 8 + n) * 4 + h] + base; mx = fmaxf(mx, l[n]); }
        float s = 0.f;
        #pragma unroll
        for (int n = 0; n < 8; ++n) { l[n] = __expf(l[n] - mx); s += l[n]; }
        float inv = 1.f / s;
        int gp = p0 + q;
        float* at = shR + 320;
        #pragma unroll
        for (int n = 0; n < 8; ++n) {
            float aa = l[n] * inv;
            at[(n * 4 + h) * 8 + q] = aa;
            if (gp < MM2) attnf[(((size_t)b * MM2 + gp) * 8 + n) * 4 + h] = aa;
        }
    }
    __syncthreads();

    // phase 3: conv MFMA. wave = group g; B-frags in registers; cols 8..15 duplicate pos 7..0
    int g = w;
    int col = lane & 15;
    int pos = col & 7;
    float aT[8];
    {
        const float* at = shR + 320;
        #pragma unroll
        for (int nn = 0; nn < 8; ++nn) aT[nn] = at[(nn * 4 + g) * 8 + pos];
    }
    f32x4 accn[4], accs[4];
    #pragma unroll
    for (int mt = 0; mt < 4; ++mt) { accn[mt] = (f32x4){0,0,0,0}; accs[mt] = (f32x4){0,0,0,0}; }

    #pragma unroll
    for (int kc = 0; kc < 8; ++kc) {
        int k0 = kc * 32 + quad * 8;
        int t = k0 >> 6, ci0 = k0 & 63;
        int cb = (g * 64 + ci0) >> 3;
        int r0 = pos * 8 + 2 * t;
        int key0 = (pos ^ (2 * t)) & 7, key1 = (pos ^ (2 * t + 1)) & 7;
        short8 n0 = *(const short8*)(sh_node + r0 * 256 + ((cb ^ key0) * 8));
        short8 n1 = *(const short8*)(sh_node + (r0 + 1) * 256 + ((cb ^ key1) * 8));
        float a0 = aT[2 * t], a1 = aT[2 * t + 1];
        union { uint4 u; short8 s; } cv;
        #pragma unroll
        for (int e = 0; e < 4; ++e) {
            float lo = fmaf(a0, b2f((u16)n0[2 * e]),     a1 * b2f((u16)n1[2 * e]));
            float hi = fmaf(a0, b2f((u16)n0[2 * e + 1]), a1 * b2f((u16)n1[2 * e + 1]));
            ((u32*)&cv.u)[e] = pk(lo, hi);
        }
        short8 bB = cv.s;
        #pragma unroll
        for (int mt = 0; mt < 4; ++mt) {
            short8 aA = *(const short8*)(wA1 + (((g * 8 + kc) * 4 + mt) * 512 + lane * 8));
            accn[mt] = __builtin_amdgcn_mfma_f32_16x16x32_bf16(aA, bB, accn[mt], 0, 0, 0);
        }
    }
    #pragma unroll
    for (int kc = 0; kc < 2; ++kc) {
        int cb = (g * 64 + kc * 32 + quad * 8) >> 3;
        short8 bS = *(const short8*)(sh_srcq + pos * 256 + ((cb ^ pos) * 8));
        #pragma unroll
        for (int mt = 0; mt < 4; ++mt) {
            short8 aS = *(const short8*)(wS1 + (((g * 2 + kc) * 4 + mt) * 512 + lane * 8));
            accs[mt] = __builtin_amdgcn_mfma_f32_16x16x32_bf16(aS, bS, accs[mt], 0, 0, 0);
        }
    }
    __syncthreads();   // src reads done; reuse sh_srcq as out tile [pos][o]

    u16* outt = sh_srcq;
    #pragma unroll
    for (int mt = 0; mt < 4; ++mt) {
        int ob = g * 64 + mt * 16 + quad * 4;
        float v[4], n1v[4];
        #pragma unroll
        for (int r = 0; r < 4; ++r) {
            int o = ob + r;
            float n1 = fmaxf(accn[mt][r] + bagg1[o], 0.f);
            float s1 = fmaxf(accs[mt][r] + bsrc1[o], 0.f);
            n1v[r] = n1;
            v[r] = n1 + s1;
        }
        if (col < 8) {
            u32* wp = (u32*)&outt[col * 256 + ob];
            wp[0] = pk(v[0], v[1]);
            wp[1] = pk(v[2], v[3]);
        }
        if (blockIdx.x == 0 && col == 0) {
            #pragma unroll
            for (int r = 0; r < 4; ++r) n1m0[b * 256 + ob + r] = n1v[r];
        }
    }
    __syncthreads();
    {
        int posw = tid >> 5, cc = (tid & 31) * 8;
        if (p0 + posw < MM)
            *(uint4*)&out1[((size_t)b * MMP + p0 + posw) * 256 + cc] = *(const uint4*)&outt[posw * 256 + cc];
    }
}

// ---------- layer2 conv + score2 (blocks x<64) + score1 (block x==64) ----------
__global__ __launch_bounds__(256) void l2conv_k(
    const u16* __restrict__ out1, const float* __restrict__ attnf,
    const float* __restrict__ gt2,
    const u16* __restrict__ wA2, const u16* __restrict__ wS2,
    const float* __restrict__ bagg2, const float* __restrict__ bsrc2,
    const float* __restrict__ gt1m0, const float* __restrict__ n1m0,
    float* __restrict__ outp, float* __restrict__ score2p, float* __restrict__ score1p) {
    __shared__ char shraw[16 * 268 * 4 * 2];
    __shared__ float shred[128];

    int tid = threadIdx.x;
    int b = blockIdx.y;

    if (blockIdx.x == 64) {            // fused score1
        float d = gt1m0[b * 256 + tid] - n1m0[b * 256 + tid];
        float v = d * d;
        #pragma unroll
        for (int off = 32; off > 0; off >>= 1) v += __shfl_down(v, off, 64);
        if ((tid & 63) == 0) shred[tid >> 6] = v;
        __syncthreads();
        if (tid == 0) score1p[b] = 1.f - __expf(-0.5f * (shred[0] + shred[1] + shred[2] + shred[3]));
        return;
    }

    int p0 = blockIdx.x * 8;
    u16* aggl = (u16*)shraw;

    {
        int pos16 = tid >> 4, cc = tid & 15;
        int pos = pos16 < 8 ? pos16 : 7;
        int m = p0 + pos;
        int c0 = cc * 16;
        int h = c0 >> 6;
        const float* arow = attnf + ((size_t)b * MM2 + m) * 32;
        #pragma unroll
        for (int t = 0; t < 4; ++t) {
            float a0 = arow[(2 * t) * 4 + h];
            float a1 = arow[(2 * t + 1) * 4 + h];
            const uint4* r0 = (const uint4*)(out1 + ((size_t)b * MMP + 1 + 8 * m + 2 * t) * 256 + c0);
            const uint4* r1 = (const uint4*)(out1 + ((size_t)b * MMP + 2 + 8 * m + 2 * t) * 256 + c0);
            u32 w[8];
            #pragma unroll
            for (int v = 0; v < 2; ++v) {
                uint4 p = r0[v], q = r1[v];
                u32 pv[4] = {p.x, p.y, p.z, p.w};
                u32 qv[4] = {q.x, q.y, q.z, q.w};
                #pragma unroll
                for (int e = 0; e < 4; ++e) {
                    float lo = fmaf(bflo(pv[e]), a0, bflo(qv[e]) * a1);
                    float hi = fmaf(bfhi(pv[e]), a0, bfhi(qv[e]) * a1);
                    w[v * 4 + e] = pk(lo, hi);
                }
            }
            u32* dst = (u32*)&aggl[pos16 * 1024 + h * 256 + t * 64 + (c0 & 63)];
            ((uint4*)dst)[0] = make_uint4(w[0], w[1], w[2], w[3]);
            ((uint4*)dst)[1] = make_uint4(w[4], w[5], w[6], w[7]);
        }
    }
    __syncthreads();

    int lane = tid & 63, g = tid >> 6;
    int col = lane & 15, quad = lane >> 4;
    f32x4 accn[4], accs[4];
    #pragma unroll
    for (int mt = 0; mt < 4; ++mt) { accn[mt] = (f32x4){0,0,0,0}; accs[mt] = (f32x4){0,0,0,0}; }

    #pragma unroll
    for (int kc = 0; kc < 8; ++kc) {
        short8 bB = *(const short8*)&aggl[col * 1024 + g * 256 + kc * 32 + quad * 8];
        #pragma unroll
        for (int mt = 0; mt < 4; ++mt) {
            short8 aA = *(const short8*)(wA2 + (((g * 8 + kc) * 4 + mt) * 512 + lane * 8));
            accn[mt] = __builtin_amdgcn_mfma_f32_16x16x32_bf16(aA, bB, accn[mt], 0, 0, 0);
        }
    }
    {
        int pcol = col < 8 ? col : 7;
        #pragma unroll
        for (int kc = 0; kc < 2; ++kc) {
            short8 bS = *(const short8*)(out1 + ((size_t)b * MMP + p0 + pcol) * 256 + g * 64 + kc * 32 + quad * 8);
            #pragma unroll
            for (int mt = 0; mt < 4; ++mt) {
                short8 aS = *(const short8*)(wS2 + (((g * 2 + kc) * 4 + mt) * 512 + lane * 8));
                accs[mt] = __builtin_amdgcn_mfma_f32_16x16x32_bf16(aS, bS, accs[mt], 0, 0, 0);
            }
        }
    }
    __syncthreads();

    float* outt = (float*)shraw;
    float* n2t  = outt + 16 * 268;
    #pragma unroll
    for (int mt = 0; mt < 4; ++mt) {
        #pragma unroll
        for (int r = 0; r < 4; ++r) {
            int o = g * 64 + mt * 16 + quad * 4 + r;
            float n2 = fmaxf(accn[mt][r] + bagg2[o], 0.f);
            float s2 = fmaxf(accs[mt][r] + bsrc2[o], 0.f);
            outt[col * 268 + o] = n2 + s2;
            n2t[col * 268 + o] = n2;
        }
    }
    __syncthreads();

    for (int j = tid; j < 512; j += 256) {
        int pos = j >> 6, cc = (j & 63) * 4;
        *(float4*)&outp[((size_t)b * MM2 + p0 + pos) * 256 + cc] = *(const float4*)&outt[pos * 268 + cc];
    }
    if (tid < 128) {
        int pos = tid >> 4, kk = tid & 15;
        const float* grow = gt2 + ((size_t)b * MM2 + p0 + pos) * 256 + kk * 16;
        const float* nrow = n2t + pos * 268 + kk * 16;
        float s = 0.f;
        #pragma unroll
        for (int c = 0; c < 16; ++c) { float d = grow[c] - nrow[c]; s = fmaf(d, d, s); }
        shred[pos * 16 + kk] = s;
    }
    __syncthreads();
    if (tid < 8) {
        float s = 0.f;
        #pragma unroll
        for (int kk = 0; kk < 16; ++kk) s += shred[tid * 16 + kk];
        score2p[(size_t)b * MM2 + p0 + tid] = 1.f - __expf(-0.5f * s);
    }
}

extern "C" void kernel_launch(void* const* d_in, const int* in_sizes, int n_in,
                              void* d_out, int out_size, void* d_ws, size_t ws_size,
                              hipStream_t stream) {
    const float* x     = (const float*)d_in[0];
    const float* gt    = (const float*)d_in[1];
    const float* watt  = (const float*)d_in[2];
    const float* batt  = (const float*)d_in[3];
    const float* wgt1  = (const float*)d_in[4];
    const float* bgt1  = (const float*)d_in[5];
    const float* wgt2  = (const float*)d_in[6];
    const float* bgt2  = (const float*)d_in[7];
    const float* wagg1 = (const float*)d_in[8];
    const float* bagg1 = (const float*)d_in[9];
    const float* wsrc1 = (const float*)d_in[10];
    const float* bsrc1 = (const float*)d_in[11];
    const float* wagg2 = (const float*)d_in[12];
    const float* bagg2 = (const float*)d_in[13];
    const float* wsrc2 = (const float*)d_in[14];
    const float* bsrc2 = (const float*)d_in[15];

    char* ws = (char*)d_ws;
    float* ws_gt2  = (float*)(ws + 0);            // 2 MB
    float* attnf   = (float*)(ws + 2097152);      // 256 KB
    float* n1m0    = (float*)(ws + 2359296);      // 4 KB
    float* gt1m0   = (float*)(ws + 2363392);      // 4 KB
    u16*   wA1     = (u16*)(ws + 2367488);        // 128 KB
    u16*   wS1     = (u16*)(ws + 2498560);        // 32 KB
    u16*   wA2     = (u16*)(ws + 2531328);        // 128 KB
    u16*   wS2     = (u16*)(ws + 2662400);        // 32 KB
    u16*   wattB   = (u16*)(ws + 2695168);        // 8 KB
    u16*   out1    = (u16*)(ws + 2703360);        // 8,421,376 B

    float* outp    = (float*)d_out;               // 2048*256
    float* score1p = outp + 524288;               // 4
    float* score2p = outp + 524292;               // 2048

    setup_k<<<dim3(912), dim3(256), 0, stream>>>(wagg1, wagg2, wsrc1, wsrc2, watt,
                                                 wA1, wA2, wS1, wS2, wattB,
                                                 gt, wgt1, bgt1, wgt2, bgt2, ws_gt2, gt1m0);
    l1fused_k<<<dim3(513, 4), dim3(256), 0, stream>>>(x, batt, wA1, wS1, wattB, bagg1, bsrc1,
                                                      attnf, out1, n1m0);
    l2conv_k<<<dim3(65, 4), dim3(256), 0, stream>>>(out1, attnf, ws_gt2, wA2, wS2, bagg2, bsrc2,
                                                    gt1m0, n1m0, outp, score2p, score1p);
}

// Round 7
// 279.315 us; speedup vs baseline: 1.9648x; 1.0760x over previous
//
#include <hip/hip_runtime.h>
#include <hip/hip_bf16.h>

typedef unsigned short u16;
typedef unsigned int   u32;
typedef __attribute__((ext_vector_type(8))) short short8;
typedef __attribute__((ext_vector_type(4))) float f32x4;

#define BB  4
#define LL  32777
#define MM  4097
#define MMP 4112
#define MM2 512

__device__ __forceinline__ float b2f(u16 u) { return __uint_as_float(((u32)u) << 16); }
__device__ __forceinline__ u16 f2bf(float f) {           // cold path only (setup swizzles)
    u32 u = __float_as_uint(f);
    return (u16)((u + 0x7fffu + ((u >> 16) & 1u)) >> 16);   // RNE
}
// HW v_cvt_pk_bf16_f32 (RNE) — a in low 16, b in high 16
__device__ __forceinline__ u32 pk(float a, float b) {
    union { __hip_bfloat162 h; u32 u; } cv;
    cv.h = __float22bfloat162_rn(make_float2(a, b));
    return cv.u;
}
__device__ __forceinline__ float bflo(u32 u) { return __uint_as_float(u << 16); }
__device__ __forceinline__ float bfhi(u32 u) { return __uint_as_float(u & 0xffff0000u); }

// ---------- setup: weight swizzles only ----------
__global__ __launch_bounds__(256) void setup_k(
    const float* __restrict__ wagg1, const float* __restrict__ wagg2,
    const float* __restrict__ wsrc1, const float* __restrict__ wsrc2,
    const float* __restrict__ watt,
    u16* __restrict__ wA1, u16* __restrict__ wA2,
    u16* __restrict__ wS1, u16* __restrict__ wS2, u16* __restrict__ wattB) {
    int idx = blockIdx.x * 256 + threadIdx.x;      // 0..167935
    if (idx < 131072) {
        int which = idx >> 16;
        int e = idx & 65535;
        int j = e & 7, lane = (e >> 3) & 63, mt = (e >> 9) & 3, kc = (e >> 11) & 7, g = (e >> 14) & 3;
        int ol = mt * 16 + (lane & 15);
        int k = kc * 32 + (lane >> 4) * 8 + j;
        int t = k >> 6, ci = k & 63;
        const float* src = which ? wagg2 : wagg1;
        u16* dst = which ? wA2 : wA1;
        dst[e] = f2bf(src[(g * 64 + ol) * 256 + ci * 4 + t]);
    } else if (idx < 163840) {
        int e2 = idx - 131072;
        int which = e2 >> 14;
        int e = e2 & 16383;
        int j = e & 7, lane = (e >> 3) & 63, mt = (e >> 9) & 3, kc = (e >> 11) & 1, g = (e >> 12) & 3;
        int ol = mt * 16 + (lane & 15);
        int k = kc * 32 + (lane >> 4) * 8 + j;
        const float* src = which ? wsrc2 : wsrc1;
        u16* dst = which ? wS2 : wS1;
        dst[e] = f2bf(src[(g * 64 + ol) * 64 + k]);
    } else {
        int e = idx - 163840;                      // 0..4095
        int j = e & 7, lane = (e >> 3) & 63, kc = e >> 9;
        int h = lane & 15, quad = lane >> 4;
        int k = kc * 32 + quad * 8 + j;
        wattB[e] = (h < 4) ? f2bf(watt[k * 4 + h]) : (u16)0;
    }
}

// ---------- fused layer1 (x<513) + gt double-GEMM (x>=513), 4 blocks/CU ----------
__global__ __launch_bounds__(256, 4) void l1fused_k(
    const float* __restrict__ x, const float* __restrict__ batt,
    const u16* __restrict__ wA1, const u16* __restrict__ wS1,
    const u16* __restrict__ wattB,
    const float* __restrict__ bagg1, const float* __restrict__ bsrc1,
    float* __restrict__ attnf, u16* __restrict__ out1, float* __restrict__ n1m0,
    const float* __restrict__ gt, const float* __restrict__ W1, const float* __restrict__ b1,
    const float* __restrict__ W2, const float* __restrict__ b2,
    float* __restrict__ gt2, float* __restrict__ gt1m0) {
    __shared__ u16   sh_node[64 * 256];    // [r=pos*8+n][cb^((pos^n)&7)] bf16, 32 KB
    __shared__ u16   sh_srcq[8 * 256];     // [q][cb^(q&7)] bf16, 4 KB; aliased as out tile
    __shared__ float shR[576];             // rdN[0..255], rdS[256..319], attn[320..575]

    int tid = threadIdx.x;
    int b = blockIdx.y;

    if (blockIdx.x >= 513) {
        // ---- fused gt GEMM: gt1 in LDS, gt2 to global ----
        float (*sh)[8] = (float(*)[8])sh_node;     // 8 KB alias
        int gi = (blockIdx.x - 513) * 4 + b;       // 0..255
        int row0 = gi * 8;
        {
            int r = tid >> 5, j = tid & 31;
            const float4* a4 = (const float4*)(gt + (size_t)(row0 + r) * 256 + j * 8);
            float4 v0 = a4[0], v1 = a4[1];
            sh[j * 8 + 0][r] = v0.x; sh[j * 8 + 1][r] = v0.y;
            sh[j * 8 + 2][r] = v0.z; sh[j * 8 + 3][r] = v0.w;
            sh[j * 8 + 4][r] = v1.x; sh[j * 8 + 5][r] = v1.y;
            sh[j * 8 + 6][r] = v1.z; sh[j * 8 + 7][r] = v1.w;
        }
        __syncthreads();
        int o = tid;
        float acc[8];
        {
            float bo = b1[o];
            #pragma unroll
            for (int i = 0; i < 8; ++i) acc[i] = bo;
        }
        #pragma unroll 4
        for (int k = 0; k < 256; ++k) {
            float wv = W1[k * 256 + o];
            const float4* ap = (const float4*)&sh[k][0];
            float4 a0 = ap[0], a1 = ap[1];
            acc[0] = fmaf(a0.x, wv, acc[0]); acc[1] = fmaf(a0.y, wv, acc[1]);
            acc[2] = fmaf(a0.z, wv, acc[2]); acc[3] = fmaf(a0.w, wv, acc[3]);
            acc[4] = fmaf(a1.x, wv, acc[4]); acc[5] = fmaf(a1.y, wv, acc[5]);
            acc[6] = fmaf(a1.z, wv, acc[6]); acc[7] = fmaf(a1.w, wv, acc[7]);
        }
        #pragma unroll
        for (int i = 0; i < 8; ++i) acc[i] = fmaxf(acc[i], 0.f);
        if ((row0 & 511) == 0) gt1m0[(row0 >> 9) * 256 + o] = acc[0];
        __syncthreads();
        #pragma unroll
        for (int i = 0; i < 8; ++i) sh[o][i] = acc[i];
        __syncthreads();
        {
            float bo = b2[o];
            #pragma unroll
            for (int i = 0; i < 8; ++i) acc[i] = bo;
        }
        #pragma unroll 4
        for (int k = 0; k < 256; ++k) {
            float wv = W2[k * 256 + o];
            const float4* ap = (const float4*)&sh[k][0];
            float4 a0 = ap[0], a1 = ap[1];
            acc[0] = fmaf(a0.x, wv, acc[0]); acc[1] = fmaf(a0.y, wv, acc[1]);
            acc[2] = fmaf(a0.z, wv, acc[2]); acc[3] = fmaf(a0.w, wv, acc[3]);
            acc[4] = fmaf(a1.x, wv, acc[4]); acc[5] = fmaf(a1.y, wv, acc[5]);
            acc[6] = fmaf(a1.z, wv, acc[6]); acc[7] = fmaf(a1.w, wv, acc[7]);
        }
        #pragma unroll
        for (int i = 0; i < 8; ++i) gt2[(size_t)(row0 + i) * 256 + o] = fmaxf(acc[i], 0.f);
        return;
    }

    int lane = tid & 63, w = tid >> 6;
    int quad = lane >> 4;
    int p0 = blockIdx.x * 8;

    // stage x slab (16 lanes cover one contiguous 1KB row; 72 rows in 5 passes)
    {
        int rslot = tid >> 4, cseg = tid & 15;
        const float* xb = x + (size_t)b * LL * 256;
        #pragma unroll
        for (int pass = 0; pass < 5; ++pass) {
            int r = pass * 16 + rslot;
            if (r < 72) {
                int grow, key; u16* dst;
                if (r < 64) {
                    int pos = r >> 3, nn = r & 7;
                    int gp = p0 + pos; int gpc = gp < MM ? gp : MM - 1;
                    grow = 1 + 8 * gpc + nn;
                    dst = sh_node + r * 256;
                    key = (pos ^ nn) & 7;
                } else {
                    int q = r - 64;
                    int gp = p0 + q; int gpc = gp < MM ? gp : MM - 1;
                    grow = gpc;
                    dst = sh_srcq + q * 256;
                    key = q & 7;
                }
                const float4* src4 = (const float4*)(xb + (size_t)grow * 256 + cseg * 16);
                float4 v0 = src4[0], v1 = src4[1], v2 = src4[2], v3 = src4[3];
                uint4 o0, o1;
                o0.x = pk(v0.x, v0.y); o0.y = pk(v0.z, v0.w);
                o0.z = pk(v1.x, v1.y); o0.w = pk(v1.z, v1.w);
                o1.x = pk(v2.x, v2.y); o1.y = pk(v2.z, v2.w);
                o1.z = pk(v3.x, v3.y); o1.w = pk(v3.z, v3.w);
                int cb0 = cseg * 2;
                *(uint4*)(dst + ((cb0 ^ key) * 8))       = o0;
                *(uint4*)(dst + (((cb0 + 1) ^ key) * 8)) = o1;
            }
        }
    }
    __syncthreads();

    // phase 1: rowdots via MFMA. wave w: node m-tile w; wave 3 also src tile.
    {
        short8 wB[8];
        #pragma unroll
        for (int kc = 0; kc < 8; ++kc) wB[kc] = *(const short8*)(wattB + kc * 512 + lane * 8);
        int m = lane & 15;            // A-frag row within tile
        int h = lane & 15;            // D col (head; valid < 4)
        {
            int r = w * 16 + m;
            int key = ((r >> 3) ^ (r & 7)) & 7;
            const u16* rowp = sh_node + r * 256;
            f32x4 acc = (f32x4){0.f, 0.f, 0.f, 0.f};
            #pragma unroll
            for (int kc = 0; kc < 8; ++kc) {
                int cb = kc * 4 + quad;
                short8 aF = *(const short8*)(rowp + ((cb ^ key) * 8));
                acc = __builtin_amdgcn_mfma_f32_16x16x32_bf16(aF, wB[kc], acc, 0, 0, 0);
            }
            if (h < 4) {
                #pragma unroll
                for (int r2 = 0; r2 < 4; ++r2)
                    shR[(w * 16 + quad * 4 + r2) * 4 + h] = acc[r2];
            }
        }
        if (w == 3) {
            int ms = m < 8 ? m : 7;
            int key = ms & 7;
            const u16* rowp = sh_srcq + ms * 256;
            f32x4 acc = (f32x4){0.f, 0.f, 0.f, 0.f};
            #pragma unroll
            for (int kc = 0; kc < 8; ++kc) {
                int cb = kc * 4 + quad;
                short8 aF = *(const short8*)(rowp + ((cb ^ key) * 8));
                acc = __builtin_amdgcn_mfma_f32_16x16x32_bf16(aF, wB[kc], acc, 0, 0, 0);
            }
            if (h < 4) {
                #pragma unroll
                for (int r2 = 0; r2 < 4; ++r2) {
                    int rr = quad * 4 + r2;
                    if (rr < 8) shR[256 + rr * 4 + h] = acc[r2];
                }
            }
        }
    }
    __syncthreads();

    // phase 2: softmax over 8 nodes per (q,h); attn -> shR[320..575] layout [n][h][8]
    if (tid < 32) {
        int q = tid >> 2, h = tid & 3;
        float base = shR[256 + q * 4 + h] + batt[h];
        float l[8], mx = -3.0e38f;
        #pragma unroll
        for (int n = 0; n < 8; ++n) { l[n] = shR[(q * 8 + n) * 4 + h] + base; mx = fmaxf(mx, l[n]); }
        float s = 0.f;
        #pragma unroll
        for (int n = 0; n < 8; ++n) { l[n] = __expf(l[n] - mx); s += l[n]; }
        float inv = 1.f / s;
        int gp = p0 + q;
        float* at = shR + 320;
        #pragma unroll
        for (int n = 0; n < 8; ++n) {
            float aa = l[n] * inv;
            at[(n * 4 + h) * 8 + q] = aa;
            if (gp < MM2) attnf[(((size_t)b * MM2 + gp) * 8 + n) * 4 + h] = aa;
        }
    }
    __syncthreads();

    // phase 3: conv MFMA. wave = group g; B-frags in registers; cols 8..15 duplicate
    int g = w;
    int col = lane & 15;
    int pos = col & 7;
    float aT[8];
    {
        const float* at = shR + 320;
        #pragma unroll
        for (int nn = 0; nn < 8; ++nn) aT[nn] = at[(nn * 4 + g) * 8 + pos];
    }
    f32x4 accn[4], accs[4];
    #pragma unroll
    for (int mt = 0; mt < 4; ++mt) { accn[mt] = (f32x4){0,0,0,0}; accs[mt] = (f32x4){0,0,0,0}; }

    #pragma unroll
    for (int kc = 0; kc < 8; ++kc) {
        int k0 = kc * 32 + quad * 8;
        int t = k0 >> 6, ci0 = k0 & 63;
        int cb = (g * 64 + ci0) >> 3;
        int r0 = pos * 8 + 2 * t;
        int key0 = (pos ^ (2 * t)) & 7, key1 = (pos ^ (2 * t + 1)) & 7;
        short8 n0 = *(const short8*)(sh_node + r0 * 256 + ((cb ^ key0) * 8));
        short8 n1 = *(const short8*)(sh_node + (r0 + 1) * 256 + ((cb ^ key1) * 8));
        float a0 = aT[2 * t], a1 = aT[2 * t + 1];
        union { uint4 u; short8 s; } cv;
        #pragma unroll
        for (int e = 0; e < 4; ++e) {
            float lo = fmaf(a0, b2f((u16)n0[2 * e]),     a1 * b2f((u16)n1[2 * e]));
            float hi = fmaf(a0, b2f((u16)n0[2 * e + 1]), a1 * b2f((u16)n1[2 * e + 1]));
            ((u32*)&cv.u)[e] = pk(lo, hi);
        }
        short8 bB = cv.s;
        #pragma unroll
        for (int mt = 0; mt < 4; ++mt) {
            short8 aA = *(const short8*)(wA1 + (((g * 8 + kc) * 4 + mt) * 512 + lane * 8));
            accn[mt] = __builtin_amdgcn_mfma_f32_16x16x32_bf16(aA, bB, accn[mt], 0, 0, 0);
        }
    }
    #pragma unroll
    for (int kc = 0; kc < 2; ++kc) {
        int cb = (g * 64 + kc * 32 + quad * 8) >> 3;
        short8 bS = *(const short8*)(sh_srcq + pos * 256 + ((cb ^ pos) * 8));
        #pragma unroll
        for (int mt = 0; mt < 4; ++mt) {
            short8 aS = *(const short8*)(wS1 + (((g * 2 + kc) * 4 + mt) * 512 + lane * 8));
            accs[mt] = __builtin_amdgcn_mfma_f32_16x16x32_bf16(aS, bS, accs[mt], 0, 0, 0);
        }
    }
    __syncthreads();   // src reads done; reuse sh_srcq as out tile [pos][o]

    u16* outt = sh_srcq;
    #pragma unroll
    for (int mt = 0; mt < 4; ++mt) {
        int ob = g * 64 + mt * 16 + quad * 4;
        float v[4], n1v[4];
        #pragma unroll
        for (int r = 0; r < 4; ++r) {
            int o = ob + r;
            float n1 = fmaxf(accn[mt][r] + bagg1[o], 0.f);
            float s1 = fmaxf(accs[mt][r] + bsrc1[o], 0.f);
            n1v[r] = n1;
            v[r] = n1 + s1;
        }
        if (col < 8) {
            u32* wp = (u32*)&outt[col * 256 + ob];
            wp[0] = pk(v[0], v[1]);
            wp[1] = pk(v[2], v[3]);
        }
        if (blockIdx.x == 0 && col == 0) {
            #pragma unroll
            for (int r = 0; r < 4; ++r) n1m0[b * 256 + ob + r] = n1v[r];
        }
    }
    __syncthreads();
    {
        int posw = tid >> 5, cc = (tid & 31) * 8;
        if (p0 + posw < MM)
            *(uint4*)&out1[((size_t)b * MMP + p0 + posw) * 256 + cc] = *(const uint4*)&outt[posw * 256 + cc];
    }
}

// ---------- layer2 conv + score2 (blocks x<64) + score1 (block x==64) ----------
__global__ __launch_bounds__(256) void l2conv_k(
    const u16* __restrict__ out1, const float* __restrict__ attnf,
    const float* __restrict__ gt2,
    const u16* __restrict__ wA2, const u16* __restrict__ wS2,
    const float* __restrict__ bagg2, const float* __restrict__ bsrc2,
    const float* __restrict__ gt1m0, const float* __restrict__ n1m0,
    float* __restrict__ outp, float* __restrict__ score2p, float* __restrict__ score1p) {
    __shared__ char shraw[16 * 268 * 4 * 2];
    __shared__ float shred[128];

    int tid = threadIdx.x;
    int b = blockIdx.y;

    if (blockIdx.x == 64) {            // fused score1
        float d = gt1m0[b * 256 + tid] - n1m0[b * 256 + tid];
        float v = d * d;
        #pragma unroll
        for (int off = 32; off > 0; off >>= 1) v += __shfl_down(v, off, 64);
        if ((tid & 63) == 0) shred[tid >> 6] = v;
        __syncthreads();
        if (tid == 0) score1p[b] = 1.f - __expf(-0.5f * (shred[0] + shred[1] + shred[2] + shred[3]));
        return;
    }

    int p0 = blockIdx.x * 8;
    u16* aggl = (u16*)shraw;

    {
        int pos16 = tid >> 4, cc = tid & 15;
        int pos = pos16 < 8 ? pos16 : 7;
        int m = p0 + pos;
        int c0 = cc * 16;
        int h = c0 >> 6;
        const float* arow = attnf + ((size_t)b * MM2 + m) * 32;
        #pragma unroll
        for (int t = 0; t < 4; ++t) {
            float a0 = arow[(2 * t) * 4 + h];
            float a1 = arow[(2 * t + 1) * 4 + h];
            const uint4* r0 = (const uint4*)(out1 + ((size_t)b * MMP + 1 + 8 * m + 2 * t) * 256 + c0);
            const uint4* r1 = (const uint4*)(out1 + ((size_t)b * MMP + 2 + 8 * m + 2 * t) * 256 + c0);
            u32 w[8];
            #pragma unroll
            for (int v = 0; v < 2; ++v) {
                uint4 p = r0[v], q = r1[v];
                u32 pv[4] = {p.x, p.y, p.z, p.w};
                u32 qv[4] = {q.x, q.y, q.z, q.w};
                #pragma unroll
                for (int e = 0; e < 4; ++e) {
                    float lo = fmaf(bflo(pv[e]), a0, bflo(qv[e]) * a1);
                    float hi = fmaf(bfhi(pv[e]), a0, bfhi(qv[e]) * a1);
                    w[v * 4 + e] = pk(lo, hi);
                }
            }
            u32* dst = (u32*)&aggl[pos16 * 1024 + h * 256 + t * 64 + (c0 & 63)];
            ((uint4*)dst)[0] = make_uint4(w[0], w[1], w[2], w[3]);
            ((uint4*)dst)[1] = make_uint4(w[4], w[5], w[6], w[7]);
        }
    }
    __syncthreads();

    int lane = tid & 63, g = tid >> 6;
    int col = lane & 15, quad = lane >> 4;
    f32x4 accn[4], accs[4];
    #pragma unroll
    for (int mt = 0; mt < 4; ++mt) { accn[mt] = (f32x4){0,0,0,0}; accs[mt] = (f32x4){0,0,0,0}; }

    #pragma unroll
    for (int kc = 0; kc < 8; ++kc) {
        short8 bB = *(const short8*)&aggl[col * 1024 + g * 256 + kc * 32 + quad * 8];
        #pragma unroll
        for (int mt = 0; mt < 4; ++mt) {
            short8 aA = *(const short8*)(wA2 + (((g * 8 + kc) * 4 + mt) * 512 + lane * 8));
            accn[mt] = __builtin_amdgcn_mfma_f32_16x16x32_bf16(aA, bB, accn[mt], 0, 0, 0);
        }
    }
    {
        int pcol = col < 8 ? col : 7;
        #pragma unroll
        for (int kc = 0; kc < 2; ++kc) {
            short8 bS = *(const short8*)(out1 + ((size_t)b * MMP + p0 + pcol) * 256 + g * 64 + kc * 32 + quad * 8);
            #pragma unroll
            for (int mt = 0; mt < 4; ++mt) {
                short8 aS = *(const short8*)(wS2 + (((g * 2 + kc) * 4 + mt) * 512 + lane * 8));
                accs[mt] = __builtin_amdgcn_mfma_f32_16x16x32_bf16(aS, bS, accs[mt], 0, 0, 0);
            }
        }
    }
    __syncthreads();

    float* outt = (float*)shraw;
    float* n2t  = outt + 16 * 268;
    #pragma unroll
    for (int mt = 0; mt < 4; ++mt) {
        #pragma unroll
        for (int r = 0; r < 4; ++r) {
            int o = g * 64 + mt * 16 + quad * 4 + r;
            float n2 = fmaxf(accn[mt][r] + bagg2[o], 0.f);
            float s2 = fmaxf(accs[mt][r] + bsrc2[o], 0.f);
            outt[col * 268 + o] = n2 + s2;
            n2t[col * 268 + o] = n2;
        }
    }
    __syncthreads();

    for (int j = tid; j < 512; j += 256) {
        int pos = j >> 6, cc = (j & 63) * 4;
        *(float4*)&outp[((size_t)b * MM2 + p0 + pos) * 256 + cc] = *(const float4*)&outt[pos * 268 + cc];
    }
    if (tid < 128) {
        int pos = tid >> 4, kk = tid & 15;
        const float* grow = gt2 + ((size_t)b * MM2 + p0 + pos) * 256 + kk * 16;
        const float* nrow = n2t + pos * 268 + kk * 16;
        float s = 0.f;
        #pragma unroll
        for (int c = 0; c < 16; ++c) { float d = grow[c] - nrow[c]; s = fmaf(d, d, s); }
        shred[pos * 16 + kk] = s;
    }
    __syncthreads();
    if (tid < 8) {
        float s = 0.f;
        #pragma unroll
        for (int kk = 0; kk < 16; ++kk) s += shred[tid * 16 + kk];
        score2p[(size_t)b * MM2 + p0 + tid] = 1.f - __expf(-0.5f * s);
    }
}

extern "C" void kernel_launch(void* const* d_in, const int* in_sizes, int n_in,
                              void* d_out, int out_size, void* d_ws, size_t ws_size,
                              hipStream_t stream) {
    const float* x     = (const float*)d_in[0];
    const float* gt    = (const float*)d_in[1];
    const float* watt  = (const float*)d_in[2];
    const float* batt  = (const float*)d_in[3];
    const float* wgt1  = (const float*)d_in[4];
    const float* bgt1  = (const float*)d_in[5];
    const float* wgt2  = (const float*)d_in[6];
    const float* bgt2  = (const float*)d_in[7];
    const float* wagg1 = (const float*)d_in[8];
    const float* bagg1 = (const float*)d_in[9];
    const float* wsrc1 = (const float*)d_in[10];
    const float* bsrc1 = (const float*)d_in[11];
    const float* wagg2 = (const float*)d_in[12];
    const float* bagg2 = (const float*)d_in[13];
    const float* wsrc2 = (const float*)d_in[14];
    const float* bsrc2 = (const float*)d_in[15];

    char* ws = (char*)d_ws;
    float* ws_gt2  = (float*)(ws + 0);            // 2 MB
    float* attnf   = (float*)(ws + 2097152);      // 256 KB
    float* n1m0    = (float*)(ws + 2359296);      // 4 KB
    float* gt1m0   = (float*)(ws + 2363392);      // 4 KB
    u16*   wA1     = (u16*)(ws + 2367488);        // 128 KB
    u16*   wS1     = (u16*)(ws + 2498560);        // 32 KB
    u16*   wA2     = (u16*)(ws + 2531328);        // 128 KB
    u16*   wS2     = (u16*)(ws + 2662400);        // 32 KB
    u16*   wattB   = (u16*)(ws + 2695168);        // 8 KB
    u16*   out1    = (u16*)(ws + 2703360);        // 8,421,376 B

    float* outp    = (float*)d_out;               // 2048*256
    float* score1p = outp + 524288;               // 4
    float* score2p = outp + 524292;               // 2048

    setup_k<<<dim3(656), dim3(256), 0, stream>>>(wagg1, wagg2, wsrc1, wsrc2, watt,
                                                 wA1, wA2, wS1, wS2, wattB);
    l1fused_k<<<dim3(577, 4), dim3(256), 0, stream>>>(x, batt, wA1, wS1, wattB, bagg1, bsrc1,
                                                      attnf, out1, n1m0,
                                                      gt, wgt1, bgt1, wgt2, bgt2, ws_gt2, gt1m0);
    l2conv_k<<<dim3(65, 4), dim3(256), 0, stream>>>(out1, attnf, ws_gt2, wA2, wS2, bagg2, bsrc2,
                                                    gt1m0, n1m0, outp, score2p, score1p);
}